// Round 1
// baseline (1692.403 us; speedup 1.0000x reference)
//
#include <hip/hip_runtime.h>

#define N_NODES 50000
#define F_IN 64
#define P_IN 2
#define D_IN 66      // F_IN + P_IN
#define H1 128
#define O_OUT 64

// h0 = concat(x, pos)  [N, 66]
__global__ void build_h0(const float* __restrict__ x, const float* __restrict__ pos,
                         float* __restrict__ h0, int n) {
    int i = blockIdx.x * blockDim.x + threadIdx.x;
    int total = n * D_IN;
    if (i >= total) return;
    int node = i / D_IN;
    int f = i - node * D_IN;
    h0[i] = (f < F_IN) ? x[node * F_IN + f] : pos[node * P_IN + (f - F_IN)];
}

// deg[dst] += 1 per edge
__global__ void deg_count(const int* __restrict__ ei, int E, float* __restrict__ deg) {
    int e = blockIdx.x * blockDim.x + threadIdx.x;
    if (e >= E) return;
    atomicAdd(&deg[ei[E + e]], 1.0f);
}

// deg -> 1/max(deg,1)
__global__ void deg_finalize(float* __restrict__ deg, int n) {
    int i = blockIdx.x * blockDim.x + threadIdx.x;
    if (i < n) deg[i] = 1.0f / fmaxf(deg[i], 1.0f);
}

// one wave per edge: agg[dst, :] += feat[src, :]
template <int FD>
__global__ void scatter_add(const int* __restrict__ ei, int E,
                            const float* __restrict__ feat, float* __restrict__ agg) {
    int gw = (int)((blockIdx.x * (unsigned)blockDim.x + threadIdx.x) >> 6);
    int lane = threadIdx.x & 63;
    if (gw >= E) return;
    int src = ei[gw];
    int dst = ei[E + gw];
    const float* fr = feat + (size_t)src * FD;
    float* ar = agg + (size_t)dst * FD;
    #pragma unroll
    for (int f = lane; f < FD; f += 64)
        atomicAdd(&ar[f], fr[f]);
}

// h1 = relu(h0 @ W1r + (agg1 * dinv) @ W1n + b1); 8 nodes per 128-thread block
__global__ __launch_bounds__(128) void layer1(
        const float* __restrict__ h0, const float* __restrict__ agg1,
        const float* __restrict__ dinv,
        const float* __restrict__ W1r, const float* __restrict__ W1n,
        const float* __restrict__ b1, float* __restrict__ h1) {
    __shared__ float sh0[8 * D_IN];
    __shared__ float sha[8 * D_IN];
    int nb = blockIdx.x * 8;                 // base node; N divisible by 8
    int h = threadIdx.x;                     // 0..127
    // coalesced flat staging (rows are contiguous)
    for (int i = h; i < 8 * D_IN; i += 128) {
        sh0[i] = h0[(size_t)nb * D_IN + i];
        sha[i] = agg1[(size_t)nb * D_IN + i];
    }
    __syncthreads();
    float accr[8], accn[8];
    #pragma unroll
    for (int n = 0; n < 8; n++) { accr[n] = 0.f; accn[n] = 0.f; }
    for (int k = 0; k < D_IN; k++) {
        float wr = W1r[k * H1 + h];
        float wn = W1n[k * H1 + h];
        #pragma unroll
        for (int n = 0; n < 8; n++) {
            accr[n] += sh0[n * D_IN + k] * wr;
            accn[n] += sha[n * D_IN + k] * wn;
        }
    }
    float bias = b1[h];
    #pragma unroll
    for (int n = 0; n < 8; n++) {
        float di = dinv[nb + n];
        float v = accr[n] + di * accn[n] + bias;
        h1[(size_t)(nb + n) * H1 + h] = fmaxf(v, 0.f);
    }
}

// h2 = h1 @ W2r + (agg2 * dinv) @ W2n + b2; 8 nodes per 64-thread block
__global__ __launch_bounds__(64) void layer2(
        const float* __restrict__ h1, const float* __restrict__ agg2,
        const float* __restrict__ dinv,
        const float* __restrict__ W2r, const float* __restrict__ W2n,
        const float* __restrict__ b2, float* __restrict__ h2) {
    __shared__ float sh1[8 * H1];
    __shared__ float sha[8 * H1];
    int nb = blockIdx.x * 8;
    int h = threadIdx.x;                     // 0..63
    for (int i = h; i < 8 * H1; i += 64) {
        sh1[i] = h1[(size_t)nb * H1 + i];
        sha[i] = agg2[(size_t)nb * H1 + i];
    }
    __syncthreads();
    float accr[8], accn[8];
    #pragma unroll
    for (int n = 0; n < 8; n++) { accr[n] = 0.f; accn[n] = 0.f; }
    for (int k = 0; k < H1; k++) {
        float wr = W2r[k * O_OUT + h];
        float wn = W2n[k * O_OUT + h];
        #pragma unroll
        for (int n = 0; n < 8; n++) {
            accr[n] += sh1[n * H1 + k] * wr;
            accn[n] += sha[n * H1 + k] * wn;
        }
    }
    float bias = b2[h];
    #pragma unroll
    for (int n = 0; n < 8; n++) {
        float di = dinv[nb + n];
        h2[(size_t)(nb + n) * O_OUT + h] = accr[n] + di * accn[n] + bias;
    }
}

// out[e] = dot(h2[src], h2[dst]); one wave per edge
__global__ void edge_out(const int* __restrict__ ei, int E,
                         const float* __restrict__ h2, float* __restrict__ out) {
    int gw = (int)((blockIdx.x * (unsigned)blockDim.x + threadIdx.x) >> 6);
    int lane = threadIdx.x & 63;
    if (gw >= E) return;
    int src = ei[gw];
    int dst = ei[E + gw];
    float v = h2[(size_t)src * O_OUT + lane] * h2[(size_t)dst * O_OUT + lane];
    #pragma unroll
    for (int off = 32; off; off >>= 1) v += __shfl_down(v, off);
    if (lane == 0) out[gw] = v;
}

extern "C" void kernel_launch(void* const* d_in, const int* in_sizes, int n_in,
                              void* d_out, int out_size, void* d_ws, size_t ws_size,
                              hipStream_t stream) {
    const float* x   = (const float*)d_in[0];
    const float* pos = (const float*)d_in[1];
    const int*   ei  = (const int*)d_in[2];
    const float* W1r = (const float*)d_in[3];
    const float* W1n = (const float*)d_in[4];
    const float* b1  = (const float*)d_in[5];
    const float* W2r = (const float*)d_in[6];
    const float* W2n = (const float*)d_in[7];
    const float* b2  = (const float*)d_in[8];
    float* out = (float*)d_out;
    const int E = in_sizes[2] / 2;
    const int N = N_NODES;

    // workspace layout: [deg | agg1 | agg2 | h0 | h1 | h2]
    float* ws   = (float*)d_ws;
    float* deg  = ws;                               // N
    float* agg1 = deg  + N;                         // N*D_IN
    float* agg2 = agg1 + (size_t)N * D_IN;          // N*H1
    float* h0   = agg2 + (size_t)N * H1;            // N*D_IN
    float* h1   = h0   + (size_t)N * D_IN;          // N*H1
    float* h2   = h1   + (size_t)N * H1;            // N*O_OUT

    // zero deg + agg1 + agg2 in one async memset (graph-capture safe)
    size_t zero_bytes = (size_t)N * (1 + D_IN + H1) * sizeof(float);
    hipMemsetAsync(d_ws, 0, zero_bytes, stream);

    build_h0<<<dim3((N * D_IN + 255) / 256), dim3(256), 0, stream>>>(x, pos, h0, N);
    deg_count<<<dim3((E + 255) / 256), dim3(256), 0, stream>>>(ei, E, deg);
    deg_finalize<<<dim3((N + 255) / 256), dim3(256), 0, stream>>>(deg, N);

    // scatter1: one wave per edge, 4 waves per 256-thread block
    scatter_add<D_IN><<<dim3((E + 3) / 4), dim3(256), 0, stream>>>(ei, E, h0, agg1);
    layer1<<<dim3(N / 8), dim3(128), 0, stream>>>(h0, agg1, deg, W1r, W1n, b1, h1);

    scatter_add<H1><<<dim3((E + 3) / 4), dim3(256), 0, stream>>>(ei, E, h1, agg2);
    layer2<<<dim3(N / 8), dim3(64), 0, stream>>>(h1, agg2, deg, W2r, W2n, b2, h2);

    edge_out<<<dim3((E + 3) / 4), dim3(256), 0, stream>>>(ei, E, h2, out);
}

// Round 2
// 1082.025 us; speedup vs baseline: 1.5641x; 1.5641x over previous
//
#include <hip/hip_runtime.h>

#define N_NODES 50000
#define F_IN 64
#define P_IN 2
#define D_IN 66      // F_IN + P_IN
#define H1 128
#define O_OUT 64

// h0 = concat(x, pos)  [N, 66]
__global__ void build_h0(const float* __restrict__ x, const float* __restrict__ pos,
                         float* __restrict__ h0, int n) {
    int i = blockIdx.x * blockDim.x + threadIdx.x;
    int total = n * D_IN;
    if (i >= total) return;
    int node = i / D_IN;
    int f = i - node * D_IN;
    h0[i] = (f < F_IN) ? x[node * F_IN + f] : pos[node * P_IN + (f - F_IN)];
}

// integer in-degree histogram
__global__ void deg_hist(const int* __restrict__ ei, int E, int* __restrict__ deg) {
    int e = blockIdx.x * blockDim.x + threadIdx.x;
    if (e >= E) return;
    atomicAdd(&deg[ei[E + e]], 1);
}

// single-block exclusive scan of deg -> offsets (+ cursor copy + dinv)
__global__ __launch_bounds__(1024) void scan_deg(const int* __restrict__ deg,
                                                 int* __restrict__ offsets,
                                                 int* __restrict__ cursor,
                                                 float* __restrict__ dinv, int n) {
    __shared__ int part[1024];
    int t = threadIdx.x;
    const int CH = (n + 1023) / 1024;
    int beg = t * CH;
    int end = beg + CH; if (end > n) end = n;
    int sum = 0;
    for (int i = beg; i < end; i++) sum += deg[i];
    part[t] = sum;
    __syncthreads();
    // Hillis-Steele inclusive scan
    for (int off = 1; off < 1024; off <<= 1) {
        int v = (t >= off) ? part[t - off] : 0;
        __syncthreads();
        part[t] += v;
        __syncthreads();
    }
    int run = (t == 0) ? 0 : part[t - 1];
    for (int i = beg; i < end; i++) {
        int d = deg[i];
        offsets[i] = run;
        cursor[i] = run;
        dinv[i] = 1.0f / fmaxf((float)d, 1.0f);
        run += d;
    }
}

// counting-sort scatter: sorted_src grouped by dst
__global__ void sort_edges(const int* __restrict__ ei, int E,
                           int* __restrict__ cursor, int* __restrict__ sorted_src) {
    int e = blockIdx.x * blockDim.x + threadIdx.x;
    if (e >= E) return;
    int src = ei[e];
    int dst = ei[E + e];
    int p = atomicAdd(&cursor[dst], 1);
    sorted_src[p] = src;
}

// one wave per dst node: agg[node,:] = sum over its srcs of feat[src,:]
template <int FD>
__global__ void gather_agg(const int* __restrict__ offsets, const int* __restrict__ deg,
                           const int* __restrict__ sorted_src,
                           const float* __restrict__ feat, float* __restrict__ agg, int n) {
    int node = (int)((blockIdx.x * (unsigned)blockDim.x + threadIdx.x) >> 6);
    int lane = threadIdx.x & 63;
    if (node >= n) return;
    int beg = offsets[node];
    int cnt = deg[node];
    bool has1 = (64 + lane) < FD;
    float a0 = 0.f, a1 = 0.f;
    for (int j = 0; j < cnt; j++) {
        int s = sorted_src[beg + j];
        const float* fr = feat + (size_t)s * FD;
        a0 += fr[lane];
        if (has1) a1 += fr[64 + lane];
    }
    float* ar = agg + (size_t)node * FD;
    ar[lane] = a0;
    if (has1) ar[64 + lane] = a1;
}

// h1 = relu(h0 @ W1r + (agg1 * dinv) @ W1n + b1); 8 nodes per 128-thread block
__global__ __launch_bounds__(128) void layer1(
        const float* __restrict__ h0, const float* __restrict__ agg1,
        const float* __restrict__ dinv,
        const float* __restrict__ W1r, const float* __restrict__ W1n,
        const float* __restrict__ b1, float* __restrict__ h1) {
    __shared__ float sh0[8 * D_IN];
    __shared__ float sha[8 * D_IN];
    int nb = blockIdx.x * 8;
    int h = threadIdx.x;
    for (int i = h; i < 8 * D_IN; i += 128) {
        sh0[i] = h0[(size_t)nb * D_IN + i];
        sha[i] = agg1[(size_t)nb * D_IN + i];
    }
    __syncthreads();
    float accr[8], accn[8];
    #pragma unroll
    for (int n = 0; n < 8; n++) { accr[n] = 0.f; accn[n] = 0.f; }
    for (int k = 0; k < D_IN; k++) {
        float wr = W1r[k * H1 + h];
        float wn = W1n[k * H1 + h];
        #pragma unroll
        for (int n = 0; n < 8; n++) {
            accr[n] += sh0[n * D_IN + k] * wr;
            accn[n] += sha[n * D_IN + k] * wn;
        }
    }
    float bias = b1[h];
    #pragma unroll
    for (int n = 0; n < 8; n++) {
        float di = dinv[nb + n];
        float v = accr[n] + di * accn[n] + bias;
        h1[(size_t)(nb + n) * H1 + h] = fmaxf(v, 0.f);
    }
}

// h2 = h1 @ W2r + (agg2 * dinv) @ W2n + b2; 8 nodes per 64-thread block
__global__ __launch_bounds__(64) void layer2(
        const float* __restrict__ h1, const float* __restrict__ agg2,
        const float* __restrict__ dinv,
        const float* __restrict__ W2r, const float* __restrict__ W2n,
        const float* __restrict__ b2, float* __restrict__ h2) {
    __shared__ float sh1[8 * H1];
    __shared__ float sha[8 * H1];
    int nb = blockIdx.x * 8;
    int h = threadIdx.x;
    for (int i = h; i < 8 * H1; i += 64) {
        sh1[i] = h1[(size_t)nb * H1 + i];
        sha[i] = agg2[(size_t)nb * H1 + i];
    }
    __syncthreads();
    float accr[8], accn[8];
    #pragma unroll
    for (int n = 0; n < 8; n++) { accr[n] = 0.f; accn[n] = 0.f; }
    for (int k = 0; k < H1; k++) {
        float wr = W2r[k * O_OUT + h];
        float wn = W2n[k * O_OUT + h];
        #pragma unroll
        for (int n = 0; n < 8; n++) {
            accr[n] += sh1[n * H1 + k] * wr;
            accn[n] += sha[n * H1 + k] * wn;
        }
    }
    float bias = b2[h];
    #pragma unroll
    for (int n = 0; n < 8; n++) {
        float di = dinv[nb + n];
        h2[(size_t)(nb + n) * O_OUT + h] = accr[n] + di * accn[n] + bias;
    }
}

// out[e] = dot(h2[src], h2[dst]); one wave per edge
__global__ void edge_out(const int* __restrict__ ei, int E,
                         const float* __restrict__ h2, float* __restrict__ out) {
    int gw = (int)((blockIdx.x * (unsigned)blockDim.x + threadIdx.x) >> 6);
    int lane = threadIdx.x & 63;
    if (gw >= E) return;
    int src = ei[gw];
    int dst = ei[E + gw];
    float v = h2[(size_t)src * O_OUT + lane] * h2[(size_t)dst * O_OUT + lane];
    #pragma unroll
    for (int off = 32; off; off >>= 1) v += __shfl_down(v, off);
    if (lane == 0) out[gw] = v;
}

extern "C" void kernel_launch(void* const* d_in, const int* in_sizes, int n_in,
                              void* d_out, int out_size, void* d_ws, size_t ws_size,
                              hipStream_t stream) {
    const float* x   = (const float*)d_in[0];
    const float* pos = (const float*)d_in[1];
    const int*   ei  = (const int*)d_in[2];
    const float* W1r = (const float*)d_in[3];
    const float* W1n = (const float*)d_in[4];
    const float* b1  = (const float*)d_in[5];
    const float* W2r = (const float*)d_in[6];
    const float* W2n = (const float*)d_in[7];
    const float* b2  = (const float*)d_in[8];
    float* out = (float*)d_out;
    const int E = in_sizes[2] / 2;
    const int N = N_NODES;

    // ---- workspace layout ----
    // ints: deg | offsets | cursor | sorted_src
    int* deg        = (int*)d_ws;                    // N
    int* offsets    = deg + N;                       // N
    int* cursor     = offsets + N;                   // N
    int* sorted_src = cursor + N;                    // E
    // floats: dinv | h0 | agg1 | h1 | h2 ; agg2 aliases [h0, agg1) span
    float* dinv = (float*)(sorted_src + E);          // N
    float* h0   = dinv + N;                          // N*D_IN
    float* agg1 = h0   + (size_t)N * D_IN;           // N*D_IN
    float* h1   = agg1 + (size_t)N * D_IN;           // N*H1
    float* h2   = h1   + (size_t)N * H1;             // N*O_OUT
    float* agg2 = h0;  // N*H1 <= N*2*D_IN, h0/agg1 dead after layer1

    // zero only the degree histogram
    hipMemsetAsync(deg, 0, (size_t)N * sizeof(int), stream);

    build_h0<<<dim3((N * D_IN + 255) / 256), dim3(256), 0, stream>>>(x, pos, h0, N);
    deg_hist<<<dim3((E + 255) / 256), dim3(256), 0, stream>>>(ei, E, deg);
    scan_deg<<<dim3(1), dim3(1024), 0, stream>>>(deg, offsets, cursor, dinv, N);
    sort_edges<<<dim3((E + 255) / 256), dim3(256), 0, stream>>>(ei, E, cursor, sorted_src);

    gather_agg<D_IN><<<dim3((N + 3) / 4), dim3(256), 0, stream>>>(
        offsets, deg, sorted_src, h0, agg1, N);
    layer1<<<dim3(N / 8), dim3(128), 0, stream>>>(h0, agg1, dinv, W1r, W1n, b1, h1);

    gather_agg<H1><<<dim3((N + 3) / 4), dim3(256), 0, stream>>>(
        offsets, deg, sorted_src, h1, agg2, N);
    layer2<<<dim3(N / 8), dim3(64), 0, stream>>>(h1, agg2, dinv, W2r, W2n, b2, h2);

    edge_out<<<dim3((E + 3) / 4), dim3(256), 0, stream>>>(ei, E, h2, out);
}

// Round 3
// 714.477 us; speedup vs baseline: 2.3687x; 1.5144x over previous
//
#include <hip/hip_runtime.h>

#define N_NODES 50000
#define F_IN 64
#define P_IN 2
#define D_IN 66
#define H1 128
#define O_OUT 64

// integer in-degree histogram
__global__ void deg_hist(const int* __restrict__ ei, int E, int* __restrict__ deg) {
    int e = blockIdx.x * blockDim.x + threadIdx.x;
    if (e >= E) return;
    atomicAdd(&deg[ei[E + e]], 1);
}

// single-block exclusive scan of deg -> offsets (+ cursor copy + dinv)
__global__ __launch_bounds__(1024) void scan_deg(const int* __restrict__ deg,
                                                 int* __restrict__ offsets,
                                                 int* __restrict__ cursor,
                                                 float* __restrict__ dinv, int n) {
    __shared__ int part[1024];
    int t = threadIdx.x;
    const int CH = (n + 1023) / 1024;
    int beg = t * CH;
    int end = beg + CH; if (end > n) end = n;
    int sum = 0;
    for (int i = beg; i < end; i++) sum += deg[i];
    part[t] = sum;
    __syncthreads();
    for (int off = 1; off < 1024; off <<= 1) {
        int v = (t >= off) ? part[t - off] : 0;
        __syncthreads();
        part[t] += v;
        __syncthreads();
    }
    int run = (t == 0) ? 0 : part[t - 1];
    for (int i = beg; i < end; i++) {
        int d = deg[i];
        offsets[i] = run;
        cursor[i] = run;
        dinv[i] = 1.0f / fmaxf((float)d, 1.0f);
        run += d;
    }
}

// counting-sort scatter: (src, edge_id) pairs grouped by dst
__global__ void sort_edges(const int* __restrict__ ei, int E,
                           int* __restrict__ cursor, int2* __restrict__ se) {
    int e = blockIdx.x * blockDim.x + threadIdx.x;
    if (e >= E) return;
    int src = ei[e];
    int dst = ei[E + e];
    int p = atomicAdd(&cursor[dst], 1);
    se[p] = make_int2(src, e);
}

// quarter-wave float4 gather: agg[node, 0:64] = sum over srcs of tbl[src, 0:64]
__global__ void gather64(const int* __restrict__ offsets, const int* __restrict__ deg,
                         const int2* __restrict__ se,
                         const float* __restrict__ tbl, float* __restrict__ agg, int n) {
    int node = (int)((blockIdx.x * (unsigned)blockDim.x + threadIdx.x) >> 6);
    int lane = threadIdx.x & 63;
    if (node >= n) return;
    int q = lane >> 4, r = lane & 15;
    int beg = offsets[node];
    int cnt = deg[node];
    float4 acc = make_float4(0.f, 0.f, 0.f, 0.f);
    for (int j = 0; j < cnt; j += 4) {
        int jj = j + q;
        if (jj < cnt) {
            int s = se[beg + jj].x;
            float4 v = ((const float4*)(tbl + (size_t)s * 64))[r];
            acc.x += v.x; acc.y += v.y; acc.z += v.z; acc.w += v.w;
        }
    }
    // combine the 4 quarters (lanes sharing r)
    acc.x += __shfl_down(acc.x, 16); acc.y += __shfl_down(acc.y, 16);
    acc.z += __shfl_down(acc.z, 16); acc.w += __shfl_down(acc.w, 16);
    acc.x += __shfl_down(acc.x, 32); acc.y += __shfl_down(acc.y, 32);
    acc.z += __shfl_down(acc.z, 32); acc.w += __shfl_down(acc.w, 32);
    if (lane < 16) ((float4*)(agg + (size_t)node * 64))[r] = acc;
}

// aggpos[node, 0:2] = sum over srcs of pos[src, 0:2]; 32 edges/iter per wave
__global__ void gather_pos(const int* __restrict__ offsets, const int* __restrict__ deg,
                           const int2* __restrict__ se,
                           const float* __restrict__ pos, float* __restrict__ aggpos, int n) {
    int node = (int)((blockIdx.x * (unsigned)blockDim.x + threadIdx.x) >> 6);
    int lane = threadIdx.x & 63;
    if (node >= n) return;
    int beg = offsets[node];
    int cnt = deg[node];
    float a = 0.f;
    for (int j0 = 0; j0 < cnt; j0 += 32) {
        int j = j0 + (lane >> 1);
        if (j < cnt) {
            int s = se[beg + j].x;
            a += pos[(size_t)s * 2 + (lane & 1)];
        }
    }
    a += __shfl_down(a, 32); a += __shfl_down(a, 16);
    a += __shfl_down(a, 8);  a += __shfl_down(a, 4);  a += __shfl_down(a, 2);
    if (lane < 2) aggpos[(size_t)node * 2 + lane] = a;
}

// h1 = relu([x|pos] @ W1r + dinv*[aggx|aggpos] @ W1n + b1); 8 nodes / 128 threads
__global__ __launch_bounds__(128) void layer1(
        const float* __restrict__ x, const float* __restrict__ pos,
        const float* __restrict__ aggx, const float* __restrict__ aggpos,
        const float* __restrict__ dinv,
        const float* __restrict__ W1r, const float* __restrict__ W1n,
        const float* __restrict__ b1, float* __restrict__ h1) {
    __shared__ float sx[8 * 64], sax[8 * 64], sp[8 * 2], sap[8 * 2];
    int nb = blockIdx.x * 8;
    int h = threadIdx.x;
    for (int i = h; i < 8 * 64; i += 128) {
        sx[i]  = x[(size_t)nb * 64 + i];
        sax[i] = aggx[(size_t)nb * 64 + i];
    }
    if (h < 16) {
        sp[h]  = pos[(size_t)nb * 2 + h];
        sap[h] = aggpos[(size_t)nb * 2 + h];
    }
    __syncthreads();
    float accr[8], accn[8];
    #pragma unroll
    for (int n = 0; n < 8; n++) { accr[n] = 0.f; accn[n] = 0.f; }
    for (int k = 0; k < 64; k++) {
        float wr = W1r[k * H1 + h];
        float wn = W1n[k * H1 + h];
        #pragma unroll
        for (int n = 0; n < 8; n++) {
            accr[n] += sx[n * 64 + k] * wr;
            accn[n] += sax[n * 64 + k] * wn;
        }
    }
    #pragma unroll
    for (int k = 0; k < 2; k++) {
        float wr = W1r[(64 + k) * H1 + h];
        float wn = W1n[(64 + k) * H1 + h];
        #pragma unroll
        for (int n = 0; n < 8; n++) {
            accr[n] += sp[n * 2 + k] * wr;
            accn[n] += sap[n * 2 + k] * wn;
        }
    }
    float bias = b1[h];
    #pragma unroll
    for (int n = 0; n < 8; n++) {
        float v = accr[n] + dinv[nb + n] * accn[n] + bias;
        h1[(size_t)(nb + n) * H1 + h] = fmaxf(v, 0.f);
    }
}

// z = h1 @ W2n  [N,64]; 8 nodes / 64 threads
__global__ __launch_bounds__(64) void compute_z(
        const float* __restrict__ h1, const float* __restrict__ W2n,
        float* __restrict__ z) {
    __shared__ float sh1[8 * H1];
    int nb = blockIdx.x * 8;
    int h = threadIdx.x;
    for (int i = h; i < 8 * H1; i += 64) sh1[i] = h1[(size_t)nb * H1 + i];
    __syncthreads();
    float acc[8];
    #pragma unroll
    for (int n = 0; n < 8; n++) acc[n] = 0.f;
    for (int k = 0; k < H1; k++) {
        float w = W2n[k * O_OUT + h];
        #pragma unroll
        for (int n = 0; n < 8; n++) acc[n] += sh1[n * H1 + k] * w;
    }
    #pragma unroll
    for (int n = 0; n < 8; n++) z[(size_t)(nb + n) * O_OUT + h] = acc[n];
}

// h2 = h1 @ W2r + dinv*aggz + b2; 8 nodes / 64 threads
__global__ __launch_bounds__(64) void layer2(
        const float* __restrict__ h1, const float* __restrict__ aggz,
        const float* __restrict__ dinv,
        const float* __restrict__ W2r, const float* __restrict__ b2,
        float* __restrict__ h2) {
    __shared__ float sh1[8 * H1];
    __shared__ float saz[8 * O_OUT];
    int nb = blockIdx.x * 8;
    int h = threadIdx.x;
    for (int i = h; i < 8 * H1; i += 64) sh1[i] = h1[(size_t)nb * H1 + i];
    for (int i = h; i < 8 * O_OUT; i += 64) saz[i] = aggz[(size_t)nb * O_OUT + i];
    __syncthreads();
    float acc[8];
    #pragma unroll
    for (int n = 0; n < 8; n++) acc[n] = 0.f;
    for (int k = 0; k < H1; k++) {
        float w = W2r[k * O_OUT + h];
        #pragma unroll
        for (int n = 0; n < 8; n++) acc[n] += sh1[n * H1 + k] * w;
    }
    float bias = b2[h];
    #pragma unroll
    for (int n = 0; n < 8; n++)
        h2[(size_t)(nb + n) * O_OUT + h] =
            acc[n] + dinv[nb + n] * saz[n * O_OUT + h] + bias;
}

// out[eid] = dot(h2[src], h2[dst]); wave per dst node, dst row in registers,
// quarter-wave float4 per edge (4 edges per iteration)
__global__ void edge_out(const int* __restrict__ offsets, const int* __restrict__ deg,
                         const int2* __restrict__ se,
                         const float* __restrict__ h2, float* __restrict__ out, int n) {
    int node = (int)((blockIdx.x * (unsigned)blockDim.x + threadIdx.x) >> 6);
    int lane = threadIdx.x & 63;
    if (node >= n) return;
    int q = lane >> 4, r = lane & 15;
    int beg = offsets[node];
    int cnt = deg[node];
    float4 d = ((const float4*)(h2 + (size_t)node * O_OUT))[r];  // replicated across quarters
    for (int j = 0; j < cnt; j += 4) {
        int jj = j + q;
        if (jj < cnt) {
            int2 p = se[beg + jj];
            float4 v = ((const float4*)(h2 + (size_t)p.x * O_OUT))[r];
            float t = d.x * v.x + d.y * v.y + d.z * v.z + d.w * v.w;
            t += __shfl_down(t, 8);
            t += __shfl_down(t, 4);
            t += __shfl_down(t, 2);
            t += __shfl_down(t, 1);
            if (r == 0) out[p.y] = t;
        }
    }
}

extern "C" void kernel_launch(void* const* d_in, const int* in_sizes, int n_in,
                              void* d_out, int out_size, void* d_ws, size_t ws_size,
                              hipStream_t stream) {
    const float* x   = (const float*)d_in[0];
    const float* pos = (const float*)d_in[1];
    const int*   ei  = (const int*)d_in[2];
    const float* W1r = (const float*)d_in[3];
    const float* W1n = (const float*)d_in[4];
    const float* b1  = (const float*)d_in[5];
    const float* W2r = (const float*)d_in[6];
    const float* W2n = (const float*)d_in[7];
    const float* b2  = (const float*)d_in[8];
    float* out = (float*)d_out;
    const int E = in_sizes[2] / 2;
    const int N = N_NODES;

    // ---- workspace layout ----
    int* deg     = (int*)d_ws;                        // N
    int* offsets = deg + N;                           // N
    int* cursor  = offsets + N;                       // N
    int2* se     = (int2*)(cursor + N);               // E pairs (8B-aligned: 3N*4 % 8 == 0)
    float* dinv   = (float*)(se + E);                 // N
    float* aggx   = dinv + N;                         // N*64   (z aliases after layer1)
    float* aggpos = aggx + (size_t)N * 64;            // N*2
    float* h1     = aggpos + (size_t)N * 2;           // N*128
    float* aggz   = h1 + (size_t)N * H1;              // N*64
    float* h2     = aggz + (size_t)N * O_OUT;         // N*64
    float* z      = aggx;  // aggx dead after layer1

    hipMemsetAsync(deg, 0, (size_t)N * sizeof(int), stream);

    deg_hist<<<dim3((E + 255) / 256), dim3(256), 0, stream>>>(ei, E, deg);
    scan_deg<<<dim3(1), dim3(1024), 0, stream>>>(deg, offsets, cursor, dinv, N);
    sort_edges<<<dim3((E + 255) / 256), dim3(256), 0, stream>>>(ei, E, cursor, se);

    gather64<<<dim3((N + 3) / 4), dim3(256), 0, stream>>>(offsets, deg, se, x, aggx, N);
    gather_pos<<<dim3((N + 3) / 4), dim3(256), 0, stream>>>(offsets, deg, se, pos, aggpos, N);
    layer1<<<dim3(N / 8), dim3(128), 0, stream>>>(x, pos, aggx, aggpos, dinv, W1r, W1n, b1, h1);

    compute_z<<<dim3(N / 8), dim3(64), 0, stream>>>(h1, W2n, z);
    gather64<<<dim3((N + 3) / 4), dim3(256), 0, stream>>>(offsets, deg, se, z, aggz, N);
    layer2<<<dim3(N / 8), dim3(64), 0, stream>>>(h1, aggz, dinv, W2r, b2, h2);

    edge_out<<<dim3((N + 3) / 4), dim3(256), 0, stream>>>(offsets, deg, se, h2, out, N);
}

// Round 4
// 633.821 us; speedup vs baseline: 2.6702x; 1.1273x over previous
//
#include <hip/hip_runtime.h>

#define N_NODES 50000
#define F_IN 64
#define P_IN 2
#define D_IN 66
#define H1 128
#define O_OUT 64

// integer in-degree histogram
__global__ void deg_hist(const int* __restrict__ ei, int E, int* __restrict__ deg) {
    int e = blockIdx.x * blockDim.x + threadIdx.x;
    if (e >= E) return;
    atomicAdd(&deg[ei[E + e]], 1);
}

// phase 1: per-block (256-elem) sums of deg
__global__ __launch_bounds__(256) void scan_phase1(const int* __restrict__ deg,
                                                   int* __restrict__ bsum, int n) {
    __shared__ int red[256];
    int t = threadIdx.x;
    int i = blockIdx.x * 256 + t;
    red[t] = (i < n) ? deg[i] : 0;
    __syncthreads();
    for (int off = 128; off; off >>= 1) {
        if (t < off) red[t] += red[t + off];
        __syncthreads();
    }
    if (t == 0) bsum[blockIdx.x] = red[0];
}

// phase 2: single-block exclusive scan of the block sums (nb <= 256)
__global__ __launch_bounds__(256) void scan_phase2(int* __restrict__ bsum, int nb) {
    __shared__ int s[256];
    int t = threadIdx.x;
    int v = (t < nb) ? bsum[t] : 0;
    s[t] = v;
    __syncthreads();
    for (int off = 1; off < 256; off <<= 1) {
        int u = (t >= off) ? s[t - off] : 0;
        __syncthreads();
        s[t] += u;
        __syncthreads();
    }
    if (t < nb) bsum[t] = s[t] - v;   // exclusive
}

// phase 3: block-local exclusive scan + block offset -> offsets/cursor/dinv
__global__ __launch_bounds__(256) void scan_phase3(const int* __restrict__ deg,
                                                   const int* __restrict__ bsum,
                                                   int* __restrict__ offsets,
                                                   int* __restrict__ cursor,
                                                   float* __restrict__ dinv, int n) {
    __shared__ int s[256];
    int t = threadIdx.x;
    int i = blockIdx.x * 256 + t;
    int d = (i < n) ? deg[i] : 0;
    s[t] = d;
    __syncthreads();
    for (int off = 1; off < 256; off <<= 1) {
        int u = (t >= off) ? s[t - off] : 0;
        __syncthreads();
        s[t] += u;
        __syncthreads();
    }
    int ex = s[t] - d + bsum[blockIdx.x];
    if (i < n) {
        offsets[i] = ex;
        cursor[i] = ex;
        dinv[i] = 1.0f / fmaxf((float)d, 1.0f);
    }
}

// counting-sort scatter: (src, edge_id) pairs grouped by dst
__global__ void sort_edges(const int* __restrict__ ei, int E,
                           int* __restrict__ cursor, int2* __restrict__ se) {
    int e = blockIdx.x * blockDim.x + threadIdx.x;
    if (e >= E) return;
    int src = ei[e];
    int dst = ei[E + e];
    int p = atomicAdd(&cursor[dst], 1);
    se[p] = make_int2(src, e);
}

// quarter-wave float4 gather: agg[node, 0:64] = sum over srcs of tbl[src, 0:64]
__global__ void gather64(const int* __restrict__ offsets, const int* __restrict__ deg,
                         const int2* __restrict__ se,
                         const float* __restrict__ tbl, float* __restrict__ agg, int n) {
    int node = (int)((blockIdx.x * (unsigned)blockDim.x + threadIdx.x) >> 6);
    int lane = threadIdx.x & 63;
    if (node >= n) return;
    int q = lane >> 4, r = lane & 15;
    int beg = offsets[node];
    int cnt = deg[node];
    float4 acc = make_float4(0.f, 0.f, 0.f, 0.f);
    for (int j = 0; j < cnt; j += 4) {
        int jj = j + q;
        if (jj < cnt) {
            int s = se[beg + jj].x;
            float4 v = ((const float4*)(tbl + (size_t)s * 64))[r];
            acc.x += v.x; acc.y += v.y; acc.z += v.z; acc.w += v.w;
        }
    }
    acc.x += __shfl_down(acc.x, 16); acc.y += __shfl_down(acc.y, 16);
    acc.z += __shfl_down(acc.z, 16); acc.w += __shfl_down(acc.w, 16);
    acc.x += __shfl_down(acc.x, 32); acc.y += __shfl_down(acc.y, 32);
    acc.z += __shfl_down(acc.z, 32); acc.w += __shfl_down(acc.w, 32);
    if (lane < 16) ((float4*)(agg + (size_t)node * 64))[r] = acc;
}

// aggpos[node, 0:2] = sum over srcs of pos[src, 0:2]; 32 edges/iter per wave
__global__ void gather_pos(const int* __restrict__ offsets, const int* __restrict__ deg,
                           const int2* __restrict__ se,
                           const float* __restrict__ pos, float* __restrict__ aggpos, int n) {
    int node = (int)((blockIdx.x * (unsigned)blockDim.x + threadIdx.x) >> 6);
    int lane = threadIdx.x & 63;
    if (node >= n) return;
    int beg = offsets[node];
    int cnt = deg[node];
    float a = 0.f;
    for (int j0 = 0; j0 < cnt; j0 += 32) {
        int j = j0 + (lane >> 1);
        if (j < cnt) {
            int s = se[beg + j].x;
            a += pos[(size_t)s * 2 + (lane & 1)];
        }
    }
    a += __shfl_down(a, 32); a += __shfl_down(a, 16);
    a += __shfl_down(a, 8);  a += __shfl_down(a, 4);  a += __shfl_down(a, 2);
    if (lane < 2) aggpos[(size_t)node * 2 + lane] = a;
}

// h1 = relu([x|pos] @ W1r + dinv*[aggx|aggpos] @ W1n + b1); 8 nodes / 128 threads
__global__ __launch_bounds__(128) void layer1(
        const float* __restrict__ x, const float* __restrict__ pos,
        const float* __restrict__ aggx, const float* __restrict__ aggpos,
        const float* __restrict__ dinv,
        const float* __restrict__ W1r, const float* __restrict__ W1n,
        const float* __restrict__ b1, float* __restrict__ h1) {
    __shared__ float sx[8 * 64], sax[8 * 64], sp[8 * 2], sap[8 * 2];
    int nb = blockIdx.x * 8;
    int h = threadIdx.x;
    for (int i = h; i < 8 * 64; i += 128) {
        sx[i]  = x[(size_t)nb * 64 + i];
        sax[i] = aggx[(size_t)nb * 64 + i];
    }
    if (h < 16) {
        sp[h]  = pos[(size_t)nb * 2 + h];
        sap[h] = aggpos[(size_t)nb * 2 + h];
    }
    __syncthreads();
    float accr[8], accn[8];
    #pragma unroll
    for (int n = 0; n < 8; n++) { accr[n] = 0.f; accn[n] = 0.f; }
    for (int k = 0; k < 64; k++) {
        float wr = W1r[k * H1 + h];
        float wn = W1n[k * H1 + h];
        #pragma unroll
        for (int n = 0; n < 8; n++) {
            accr[n] += sx[n * 64 + k] * wr;
            accn[n] += sax[n * 64 + k] * wn;
        }
    }
    #pragma unroll
    for (int k = 0; k < 2; k++) {
        float wr = W1r[(64 + k) * H1 + h];
        float wn = W1n[(64 + k) * H1 + h];
        #pragma unroll
        for (int n = 0; n < 8; n++) {
            accr[n] += sp[n * 2 + k] * wr;
            accn[n] += sap[n * 2 + k] * wn;
        }
    }
    float bias = b1[h];
    #pragma unroll
    for (int n = 0; n < 8; n++) {
        float v = accr[n] + dinv[nb + n] * accn[n] + bias;
        h1[(size_t)(nb + n) * H1 + h] = fmaxf(v, 0.f);
    }
}

// z = h1 @ W2n  [N,64]; 8 nodes / 64 threads
__global__ __launch_bounds__(64) void compute_z(
        const float* __restrict__ h1, const float* __restrict__ W2n,
        float* __restrict__ z) {
    __shared__ float sh1[8 * H1];
    int nb = blockIdx.x * 8;
    int h = threadIdx.x;
    for (int i = h; i < 8 * H1; i += 64) sh1[i] = h1[(size_t)nb * H1 + i];
    __syncthreads();
    float acc[8];
    #pragma unroll
    for (int n = 0; n < 8; n++) acc[n] = 0.f;
    for (int k = 0; k < H1; k++) {
        float w = W2n[k * O_OUT + h];
        #pragma unroll
        for (int n = 0; n < 8; n++) acc[n] += sh1[n * H1 + k] * w;
    }
    #pragma unroll
    for (int n = 0; n < 8; n++) z[(size_t)(nb + n) * O_OUT + h] = acc[n];
}

// h2 = h1 @ W2r + dinv*aggz + b2; 8 nodes / 64 threads
__global__ __launch_bounds__(64) void layer2(
        const float* __restrict__ h1, const float* __restrict__ aggz,
        const float* __restrict__ dinv,
        const float* __restrict__ W2r, const float* __restrict__ b2,
        float* __restrict__ h2) {
    __shared__ float sh1[8 * H1];
    __shared__ float saz[8 * O_OUT];
    int nb = blockIdx.x * 8;
    int h = threadIdx.x;
    for (int i = h; i < 8 * H1; i += 64) sh1[i] = h1[(size_t)nb * H1 + i];
    for (int i = h; i < 8 * O_OUT; i += 64) saz[i] = aggz[(size_t)nb * O_OUT + i];
    __syncthreads();
    float acc[8];
    #pragma unroll
    for (int n = 0; n < 8; n++) acc[n] = 0.f;
    for (int k = 0; k < H1; k++) {
        float w = W2r[k * O_OUT + h];
        #pragma unroll
        for (int n = 0; n < 8; n++) acc[n] += sh1[n * H1 + k] * w;
    }
    float bias = b2[h];
    #pragma unroll
    for (int n = 0; n < 8; n++)
        h2[(size_t)(nb + n) * O_OUT + h] =
            acc[n] + dinv[nb + n] * saz[n * O_OUT + h] + bias;
}

// out[eid] = dot(h2[src], h2[dst]); wave per dst node, dst row in registers
__global__ void edge_out(const int* __restrict__ offsets, const int* __restrict__ deg,
                         const int2* __restrict__ se,
                         const float* __restrict__ h2, float* __restrict__ out, int n) {
    int node = (int)((blockIdx.x * (unsigned)blockDim.x + threadIdx.x) >> 6);
    int lane = threadIdx.x & 63;
    if (node >= n) return;
    int q = lane >> 4, r = lane & 15;
    int beg = offsets[node];
    int cnt = deg[node];
    float4 d = ((const float4*)(h2 + (size_t)node * O_OUT))[r];
    for (int j = 0; j < cnt; j += 4) {
        int jj = j + q;
        if (jj < cnt) {
            int2 p = se[beg + jj];
            float4 v = ((const float4*)(h2 + (size_t)p.x * O_OUT))[r];
            float t = d.x * v.x + d.y * v.y + d.z * v.z + d.w * v.w;
            t += __shfl_down(t, 8);
            t += __shfl_down(t, 4);
            t += __shfl_down(t, 2);
            t += __shfl_down(t, 1);
            if (r == 0) out[p.y] = t;
        }
    }
}

extern "C" void kernel_launch(void* const* d_in, const int* in_sizes, int n_in,
                              void* d_out, int out_size, void* d_ws, size_t ws_size,
                              hipStream_t stream) {
    const float* x   = (const float*)d_in[0];
    const float* pos = (const float*)d_in[1];
    const int*   ei  = (const int*)d_in[2];
    const float* W1r = (const float*)d_in[3];
    const float* W1n = (const float*)d_in[4];
    const float* b1  = (const float*)d_in[5];
    const float* W2r = (const float*)d_in[6];
    const float* W2n = (const float*)d_in[7];
    const float* b2  = (const float*)d_in[8];
    float* out = (float*)d_out;
    const int E = in_sizes[2] / 2;
    const int N = N_NODES;
    const int NB = (N + 255) / 256;   // 196 scan blocks

    // ---- workspace layout ----
    int* deg     = (int*)d_ws;                        // N
    int* offsets = deg + N;                           // N
    int* cursor  = offsets + N;                       // N
    int* bsum    = cursor + N;                        // NB (pad to even)
    int2* se     = (int2*)(bsum + ((NB + 1) & ~1));   // E pairs, 8B-aligned
    float* dinv   = (float*)(se + E);                 // N
    float* aggx   = dinv + N;                         // N*64   (z aliases after layer1)
    float* aggpos = aggx + (size_t)N * 64;            // N*2
    float* h1     = aggpos + (size_t)N * 2;           // N*128
    float* aggz   = h1 + (size_t)N * H1;              // N*64
    float* h2     = aggz + (size_t)N * O_OUT;         // N*64
    float* z      = aggx;  // aggx dead after layer1

    hipMemsetAsync(deg, 0, (size_t)N * sizeof(int), stream);

    deg_hist<<<dim3((E + 255) / 256), dim3(256), 0, stream>>>(ei, E, deg);
    scan_phase1<<<dim3(NB), dim3(256), 0, stream>>>(deg, bsum, N);
    scan_phase2<<<dim3(1), dim3(256), 0, stream>>>(bsum, NB);
    scan_phase3<<<dim3(NB), dim3(256), 0, stream>>>(deg, bsum, offsets, cursor, dinv, N);
    sort_edges<<<dim3((E + 255) / 256), dim3(256), 0, stream>>>(ei, E, cursor, se);

    gather64<<<dim3((N + 3) / 4), dim3(256), 0, stream>>>(offsets, deg, se, x, aggx, N);
    gather_pos<<<dim3((N + 3) / 4), dim3(256), 0, stream>>>(offsets, deg, se, pos, aggpos, N);
    layer1<<<dim3(N / 8), dim3(128), 0, stream>>>(x, pos, aggx, aggpos, dinv, W1r, W1n, b1, h1);

    compute_z<<<dim3(N / 8), dim3(64), 0, stream>>>(h1, W2n, z);
    gather64<<<dim3((N + 3) / 4), dim3(256), 0, stream>>>(offsets, deg, se, z, aggz, N);
    layer2<<<dim3(N / 8), dim3(64), 0, stream>>>(h1, aggz, dinv, W2r, b2, h2);

    edge_out<<<dim3((N + 3) / 4), dim3(256), 0, stream>>>(offsets, deg, se, h2, out, N);
}

// Round 5
// 453.224 us; speedup vs baseline: 3.7341x; 1.3985x over previous
//
#include <hip/hip_runtime.h>

#define N_NODES 50000
#define H1 128
#define O_OUT 64
#define NBKT 196          // ceil(50000/256) dst buckets of 256 nodes
#define CTILE 4096        // edges per coarse-scatter tile

__device__ inline unsigned short f2bf(float f) {
    union { float f; unsigned u; } c; c.f = f;
    unsigned u = c.u;
    return (unsigned short)((u + 0x7FFF + ((u >> 16) & 1)) >> 16);  // RNE
}
__device__ inline float bf2f(unsigned short h) {
    union { unsigned u; float f; } c; c.u = ((unsigned)h) << 16;
    return c.f;
}

// cast fp32 table -> bf16 table (float4 -> ushort4)
__global__ void xcast(const float* __restrict__ x, unsigned short* __restrict__ xb,
                      int total4) {
    int i = blockIdx.x * blockDim.x + threadIdx.x;
    if (i >= total4) return;
    float4 v = ((const float4*)x)[i];
    ushort4 o;
    o.x = f2bf(v.x); o.y = f2bf(v.y); o.z = f2bf(v.z); o.w = f2bf(v.w);
    ((ushort4*)xb)[i] = o;
}

// A: coarse bucket histogram (bucket = dst>>8)
__global__ __launch_bounds__(256) void bucket_hist(const int* __restrict__ ei, int E,
                                                   int* __restrict__ bcount) {
    __shared__ int h[256];
    int t = threadIdx.x;
    h[t] = 0;
    __syncthreads();
    for (int e = blockIdx.x * 256 + t; e < E; e += gridDim.x * 256)
        atomicAdd(&h[ei[E + e] >> 8], 1);
    __syncthreads();
    if (t < NBKT && h[t]) atomicAdd(&bcount[t], h[t]);
}

// B: scan 196 bucket counts -> bucket_base[197] + cursor copy
__global__ __launch_bounds__(256) void bucket_scan(const int* __restrict__ bcount,
                                                   int* __restrict__ bbase,
                                                   int* __restrict__ bcursor) {
    __shared__ int s[256];
    int t = threadIdx.x;
    int v = (t < NBKT) ? bcount[t] : 0;
    s[t] = v;
    __syncthreads();
    for (int off = 1; off < 256; off <<= 1) {
        int u = (t >= off) ? s[t - off] : 0;
        __syncthreads();
        s[t] += u;
        __syncthreads();
    }
    if (t < NBKT) { bbase[t] = s[t] - v; bcursor[t] = s[t] - v; }
    if (t == 0) bbase[NBKT] = s[255];
}

// C: coarse scatter — tile of 4096 edges LDS-sorted by bucket, runs written
// contiguously at atomically-reserved global bases. Entry: (src, dstlow<<21|eid)
__global__ __launch_bounds__(256) void coarse_scatter(const int* __restrict__ ei, int E,
                                                      int* __restrict__ bcursor,
                                                      int2* __restrict__ se) {
    __shared__ int2 buf[CTILE];          // 32 KB
    __shared__ int hist[256], sscan[256], lstart[257], lcur[256], gbase[256];
    int t = threadIdx.x;
    int tile0 = blockIdx.x * CTILE;
    int cnt = E - tile0; if (cnt > CTILE) cnt = CTILE;
    hist[t] = 0;
    __syncthreads();
    int2 ent[CTILE / 256];
    int bkt[CTILE / 256];
    #pragma unroll
    for (int k = 0; k < CTILE / 256; k++) {
        int e = tile0 + k * 256 + t;
        if (e < E) {
            int src = ei[e];
            int dst = ei[E + e];
            bkt[k] = dst >> 8;
            ent[k] = make_int2(src, ((dst & 255) << 21) | e);
            atomicAdd(&hist[bkt[k]], 1);
        } else bkt[k] = -1;
    }
    __syncthreads();
    int hv = hist[t];
    sscan[t] = hv;
    __syncthreads();
    for (int off = 1; off < 256; off <<= 1) {
        int u = (t >= off) ? sscan[t - off] : 0;
        __syncthreads();
        sscan[t] += u;
        __syncthreads();
    }
    lstart[t] = sscan[t] - hv;
    lcur[t] = sscan[t] - hv;
    if (t == 0) lstart[256] = cnt;
    if (t < NBKT && hv > 0) gbase[t] = atomicAdd(&bcursor[t], hv);
    __syncthreads();
    #pragma unroll
    for (int k = 0; k < CTILE / 256; k++) {
        if (bkt[k] >= 0) {
            int p = atomicAdd(&lcur[bkt[k]], 1);
            buf[p] = ent[k];
        }
    }
    __syncthreads();
    for (int i = t; i < cnt; i += 256) {
        int lo = 0, hi = 255;
        while (lo < hi) {                 // find b: lstart[b] <= i < lstart[b+1]
            int mid = (lo + hi) >> 1;
            if (lstart[mid + 1] <= i) lo = mid + 1; else hi = mid;
        }
        se[gbase[lo] + (i - lstart[lo])] = buf[i];
    }
}

// D: fine sort within one bucket (in place) + emit offsets/deg/dinv
__global__ __launch_bounds__(256) void fine_sort(int2* __restrict__ se,
                                                 const int* __restrict__ bbase,
                                                 int* __restrict__ offsets,
                                                 int* __restrict__ deg,
                                                 float* __restrict__ dinv, int n) {
    __shared__ int2 buf[9216];           // 72 KB; bucket max ~8.6K entries
    __shared__ int hist[256], lstart[256], lcur[256];
    int t = threadIdx.x;
    int b = blockIdx.x;
    int node0 = b * 256;
    int nnodes = n - node0; if (nnodes > 256) nnodes = 256;
    int beg = bbase[b], end = bbase[b + 1];
    hist[t] = 0;
    __syncthreads();
    for (int i = beg + t; i < end; i += 256)
        atomicAdd(&hist[se[i].y >> 21], 1);
    __syncthreads();
    int hv = hist[t];
    lstart[t] = hv;
    __syncthreads();
    for (int off = 1; off < 256; off <<= 1) {
        int u = (t >= off) ? lstart[t - off] : 0;
        __syncthreads();
        lstart[t] += u;
        __syncthreads();
    }
    int ex = lstart[t] - hv;
    lcur[t] = ex;
    if (t < nnodes) {
        offsets[node0 + t] = beg + ex;
        deg[node0 + t] = hv;
        dinv[node0 + t] = 1.0f / fmaxf((float)hv, 1.0f);
    }
    __syncthreads();
    for (int i = beg + t; i < end; i += 256) {
        int2 v = se[i];
        int p = atomicAdd(&lcur[v.y >> 21], 1);
        buf[p] = make_int2(v.x, v.y & 0x1FFFFF);   // (src, eid)
    }
    __syncthreads();
    int cnt = end - beg;
    for (int i = t; i < cnt; i += 256)
        se[beg + i] = buf[i];
}

// quarter-wave bf16 gather: agg[node,0:64] = sum over srcs of tbl[src,0:64]
__global__ void gather64_bf16(const int* __restrict__ offsets, const int* __restrict__ deg,
                              const int2* __restrict__ se,
                              const unsigned short* __restrict__ tbl,
                              float* __restrict__ agg, int n) {
    int node = (int)((blockIdx.x * (unsigned)blockDim.x + threadIdx.x) >> 6);
    int lane = threadIdx.x & 63;
    if (node >= n) return;
    int q = lane >> 4, r = lane & 15;
    int beg = offsets[node];
    int cnt = deg[node];
    float4 acc = make_float4(0.f, 0.f, 0.f, 0.f);
    for (int j = 0; j < cnt; j += 4) {
        int jj = j + q;
        if (jj < cnt) {
            int s = se[beg + jj].x;
            ushort4 v = ((const ushort4*)(tbl + (size_t)s * 64))[r];
            acc.x += bf2f(v.x); acc.y += bf2f(v.y);
            acc.z += bf2f(v.z); acc.w += bf2f(v.w);
        }
    }
    acc.x += __shfl_down(acc.x, 16); acc.y += __shfl_down(acc.y, 16);
    acc.z += __shfl_down(acc.z, 16); acc.w += __shfl_down(acc.w, 16);
    acc.x += __shfl_down(acc.x, 32); acc.y += __shfl_down(acc.y, 32);
    acc.z += __shfl_down(acc.z, 32); acc.w += __shfl_down(acc.w, 32);
    if (lane < 16) ((float4*)(agg + (size_t)node * 64))[r] = acc;
}

// aggpos[node,0:2] = sum over srcs of pos[src,0:2]
__global__ void gather_pos(const int* __restrict__ offsets, const int* __restrict__ deg,
                           const int2* __restrict__ se,
                           const float* __restrict__ pos, float* __restrict__ aggpos, int n) {
    int node = (int)((blockIdx.x * (unsigned)blockDim.x + threadIdx.x) >> 6);
    int lane = threadIdx.x & 63;
    if (node >= n) return;
    int beg = offsets[node];
    int cnt = deg[node];
    float a = 0.f;
    for (int j0 = 0; j0 < cnt; j0 += 32) {
        int j = j0 + (lane >> 1);
        if (j < cnt) {
            int s = se[beg + j].x;
            a += pos[(size_t)s * 2 + (lane & 1)];
        }
    }
    a += __shfl_down(a, 32); a += __shfl_down(a, 16);
    a += __shfl_down(a, 8);  a += __shfl_down(a, 4);  a += __shfl_down(a, 2);
    if (lane < 2) aggpos[(size_t)node * 2 + lane] = a;
}

// h1 = relu([x|pos] @ W1r + dinv*[aggx|aggpos] @ W1n + b1); 8 nodes / 128 threads
__global__ __launch_bounds__(128) void layer1(
        const float* __restrict__ x, const float* __restrict__ pos,
        const float* __restrict__ aggx, const float* __restrict__ aggpos,
        const float* __restrict__ dinv,
        const float* __restrict__ W1r, const float* __restrict__ W1n,
        const float* __restrict__ b1, float* __restrict__ h1) {
    __shared__ float sx[8 * 64], sax[8 * 64], sp[8 * 2], sap[8 * 2];
    int nb = blockIdx.x * 8;
    int h = threadIdx.x;
    for (int i = h; i < 8 * 64; i += 128) {
        sx[i]  = x[(size_t)nb * 64 + i];
        sax[i] = aggx[(size_t)nb * 64 + i];
    }
    if (h < 16) {
        sp[h]  = pos[(size_t)nb * 2 + h];
        sap[h] = aggpos[(size_t)nb * 2 + h];
    }
    __syncthreads();
    float accr[8], accn[8];
    #pragma unroll
    for (int n = 0; n < 8; n++) { accr[n] = 0.f; accn[n] = 0.f; }
    for (int k = 0; k < 64; k++) {
        float wr = W1r[k * H1 + h];
        float wn = W1n[k * H1 + h];
        #pragma unroll
        for (int n = 0; n < 8; n++) {
            accr[n] += sx[n * 64 + k] * wr;
            accn[n] += sax[n * 64 + k] * wn;
        }
    }
    #pragma unroll
    for (int k = 0; k < 2; k++) {
        float wr = W1r[(64 + k) * H1 + h];
        float wn = W1n[(64 + k) * H1 + h];
        #pragma unroll
        for (int n = 0; n < 8; n++) {
            accr[n] += sp[n * 2 + k] * wr;
            accn[n] += sap[n * 2 + k] * wn;
        }
    }
    float bias = b1[h];
    #pragma unroll
    for (int n = 0; n < 8; n++) {
        float v = accr[n] + dinv[nb + n] * accn[n] + bias;
        h1[(size_t)(nb + n) * H1 + h] = fmaxf(v, 0.f);
    }
}

// z = bf16(h1 @ W2n)  [N,64]
__global__ __launch_bounds__(64) void compute_z(
        const float* __restrict__ h1, const float* __restrict__ W2n,
        unsigned short* __restrict__ z) {
    __shared__ float sh1[8 * H1];
    int nb = blockIdx.x * 8;
    int h = threadIdx.x;
    for (int i = h; i < 8 * H1; i += 64) sh1[i] = h1[(size_t)nb * H1 + i];
    __syncthreads();
    float acc[8];
    #pragma unroll
    for (int n = 0; n < 8; n++) acc[n] = 0.f;
    for (int k = 0; k < H1; k++) {
        float w = W2n[k * O_OUT + h];
        #pragma unroll
        for (int n = 0; n < 8; n++) acc[n] += sh1[n * H1 + k] * w;
    }
    #pragma unroll
    for (int n = 0; n < 8; n++) z[(size_t)(nb + n) * O_OUT + h] = f2bf(acc[n]);
}

// h2 = bf16(h1 @ W2r + dinv*aggz + b2)
__global__ __launch_bounds__(64) void layer2(
        const float* __restrict__ h1, const float* __restrict__ aggz,
        const float* __restrict__ dinv,
        const float* __restrict__ W2r, const float* __restrict__ b2,
        unsigned short* __restrict__ h2) {
    __shared__ float sh1[8 * H1];
    __shared__ float saz[8 * O_OUT];
    int nb = blockIdx.x * 8;
    int h = threadIdx.x;
    for (int i = h; i < 8 * H1; i += 64) sh1[i] = h1[(size_t)nb * H1 + i];
    for (int i = h; i < 8 * O_OUT; i += 64) saz[i] = aggz[(size_t)nb * O_OUT + i];
    __syncthreads();
    float acc[8];
    #pragma unroll
    for (int n = 0; n < 8; n++) acc[n] = 0.f;
    for (int k = 0; k < H1; k++) {
        float w = W2r[k * O_OUT + h];
        #pragma unroll
        for (int n = 0; n < 8; n++) acc[n] += sh1[n * H1 + k] * w;
    }
    float bias = b2[h];
    #pragma unroll
    for (int n = 0; n < 8; n++)
        h2[(size_t)(nb + n) * O_OUT + h] =
            f2bf(acc[n] + dinv[nb + n] * saz[n * O_OUT + h] + bias);
}

// out[eid] = dot(h2[src], h2[dst]) in bf16 rows / fp32 accumulate
__global__ void edge_out(const int* __restrict__ offsets, const int* __restrict__ deg,
                         const int2* __restrict__ se,
                         const unsigned short* __restrict__ h2,
                         float* __restrict__ out, int n) {
    int node = (int)((blockIdx.x * (unsigned)blockDim.x + threadIdx.x) >> 6);
    int lane = threadIdx.x & 63;
    if (node >= n) return;
    int q = lane >> 4, r = lane & 15;
    int beg = offsets[node];
    int cnt = deg[node];
    ushort4 du = ((const ushort4*)(h2 + (size_t)node * 64))[r];
    float d0 = bf2f(du.x), d1 = bf2f(du.y), d2 = bf2f(du.z), d3 = bf2f(du.w);
    for (int j = 0; j < cnt; j += 4) {
        int jj = j + q;
        if (jj < cnt) {
            int2 p = se[beg + jj];
            ushort4 vu = ((const ushort4*)(h2 + (size_t)p.x * 64))[r];
            float t = d0 * bf2f(vu.x) + d1 * bf2f(vu.y)
                    + d2 * bf2f(vu.z) + d3 * bf2f(vu.w);
            t += __shfl_down(t, 8);
            t += __shfl_down(t, 4);
            t += __shfl_down(t, 2);
            t += __shfl_down(t, 1);
            if (r == 0) out[p.y] = t;
        }
    }
}

extern "C" void kernel_launch(void* const* d_in, const int* in_sizes, int n_in,
                              void* d_out, int out_size, void* d_ws, size_t ws_size,
                              hipStream_t stream) {
    const float* x   = (const float*)d_in[0];
    const float* pos = (const float*)d_in[1];
    const int*   ei  = (const int*)d_in[2];
    const float* W1r = (const float*)d_in[3];
    const float* W1n = (const float*)d_in[4];
    const float* b1  = (const float*)d_in[5];
    const float* W2r = (const float*)d_in[6];
    const float* W2n = (const float*)d_in[7];
    const float* b2  = (const float*)d_in[8];
    float* out = (float*)d_out;
    const int E = in_sizes[2] / 2;
    const int N = N_NODES;

    // ---- workspace layout ----
    int* bcount  = (int*)d_ws;                        // 200
    int* bbase   = bcount + 200;                      // 200 (197 used)
    int* bcursor = bbase + 200;                       // 200
    int* offsets = bcursor + 200;                     // N
    int* deg     = offsets + N;                       // N
    int2* se     = (int2*)(deg + N);                  // E pairs (8B-aligned)
    float* dinv   = (float*)(se + E);                 // N
    float* aggx   = dinv + N;                         // N*64
    float* aggpos = aggx + (size_t)N * 64;            // N*2
    float* h1     = aggpos + (size_t)N * 2;           // N*128
    float* aggz   = h1 + (size_t)N * H1;              // N*64
    unsigned short* xb = (unsigned short*)(aggz + (size_t)N * 64);  // N*64 bf16
    unsigned short* zb = xb + (size_t)N * 64;                       // N*64 bf16
    unsigned short* h2 = zb + (size_t)N * 64;                       // N*64 bf16

    hipMemsetAsync(bcount, 0, 200 * sizeof(int), stream);

    xcast<<<dim3((N * 64 / 4 + 255) / 256), dim3(256), 0, stream>>>(x, xb, N * 16);
    bucket_hist<<<dim3(512), dim3(256), 0, stream>>>(ei, E, bcount);
    bucket_scan<<<dim3(1), dim3(256), 0, stream>>>(bcount, bbase, bcursor);
    coarse_scatter<<<dim3((E + CTILE - 1) / CTILE), dim3(256), 0, stream>>>(ei, E, bcursor, se);
    fine_sort<<<dim3(NBKT), dim3(256), 0, stream>>>(se, bbase, offsets, deg, dinv, N);

    gather64_bf16<<<dim3((N + 3) / 4), dim3(256), 0, stream>>>(offsets, deg, se, xb, aggx, N);
    gather_pos<<<dim3((N + 3) / 4), dim3(256), 0, stream>>>(offsets, deg, se, pos, aggpos, N);
    layer1<<<dim3(N / 8), dim3(128), 0, stream>>>(x, pos, aggx, aggpos, dinv, W1r, W1n, b1, h1);

    compute_z<<<dim3(N / 8), dim3(64), 0, stream>>>(h1, W2n, zb);
    gather64_bf16<<<dim3((N + 3) / 4), dim3(256), 0, stream>>>(offsets, deg, se, zb, aggz, N);
    layer2<<<dim3(N / 8), dim3(64), 0, stream>>>(h1, aggz, dinv, W2r, b2, h2);

    edge_out<<<dim3((N + 3) / 4), dim3(256), 0, stream>>>(offsets, deg, se, h2, out, N);
}

// Round 6
// 380.443 us; speedup vs baseline: 4.4485x; 1.1913x over previous
//
#include <hip/hip_runtime.h>

#define N_NODES 50000
#define H1 128
#define O_OUT 64
#define NBKT 196          // ceil(50000/256) dst buckets of 256 nodes
#define CTILE 4096        // edges per coarse-scatter tile

__device__ inline unsigned short f2bf(float f) {
    union { float f; unsigned u; } c; c.f = f;
    unsigned u = c.u;
    return (unsigned short)((u + 0x7FFF + ((u >> 16) & 1)) >> 16);  // RNE
}
// unpack packed pair of bf16 (one uint) -> two floats (shift / mask only)
__device__ inline void bf2x2(unsigned u, float& lo, float& hi) {
    union { unsigned u; float f; } a, b;
    a.u = u << 16; b.u = u & 0xFFFF0000u;
    lo = a.f; hi = b.f;
}

// cast fp32 table -> bf16 table (float4 -> ushort4)
__global__ void xcast(const float* __restrict__ x, unsigned short* __restrict__ xb,
                      int total4) {
    int i = blockIdx.x * blockDim.x + threadIdx.x;
    if (i >= total4) return;
    float4 v = ((const float4*)x)[i];
    ushort4 o;
    o.x = f2bf(v.x); o.y = f2bf(v.y); o.z = f2bf(v.z); o.w = f2bf(v.w);
    ((ushort4*)xb)[i] = o;
}

// A: coarse bucket histogram (bucket = dst>>8)
__global__ __launch_bounds__(256) void bucket_hist(const int* __restrict__ ei, int E,
                                                   int* __restrict__ bcount) {
    __shared__ int h[256];
    int t = threadIdx.x;
    h[t] = 0;
    __syncthreads();
    for (int e = blockIdx.x * 256 + t; e < E; e += gridDim.x * 256)
        atomicAdd(&h[ei[E + e] >> 8], 1);
    __syncthreads();
    if (t < NBKT && h[t]) atomicAdd(&bcount[t], h[t]);
}

// B: scan 196 bucket counts -> bucket_base[197] + cursor copy
__global__ __launch_bounds__(256) void bucket_scan(const int* __restrict__ bcount,
                                                   int* __restrict__ bbase,
                                                   int* __restrict__ bcursor) {
    __shared__ int s[256];
    int t = threadIdx.x;
    int v = (t < NBKT) ? bcount[t] : 0;
    s[t] = v;
    __syncthreads();
    for (int off = 1; off < 256; off <<= 1) {
        int u = (t >= off) ? s[t - off] : 0;
        __syncthreads();
        s[t] += u;
        __syncthreads();
    }
    if (t < NBKT) { bbase[t] = s[t] - v; bcursor[t] = s[t] - v; }
    if (t == 0) bbase[NBKT] = s[255];
}

// C: coarse scatter — tile of 4096 edges LDS-sorted by bucket, runs written
// contiguously at atomically-reserved global bases. Entry: (src, dstlow<<21|eid)
__global__ __launch_bounds__(256) void coarse_scatter(const int* __restrict__ ei, int E,
                                                      int* __restrict__ bcursor,
                                                      int2* __restrict__ se) {
    __shared__ int2 buf[CTILE];          // 32 KB
    __shared__ int hist[256], sscan[256], lstart[257], lcur[256], gbase[256];
    int t = threadIdx.x;
    int tile0 = blockIdx.x * CTILE;
    int cnt = E - tile0; if (cnt > CTILE) cnt = CTILE;
    hist[t] = 0;
    __syncthreads();
    int2 ent[CTILE / 256];
    int bkt[CTILE / 256];
    #pragma unroll
    for (int k = 0; k < CTILE / 256; k++) {
        int e = tile0 + k * 256 + t;
        if (e < E) {
            int src = ei[e];
            int dst = ei[E + e];
            bkt[k] = dst >> 8;
            ent[k] = make_int2(src, ((dst & 255) << 21) | e);
            atomicAdd(&hist[bkt[k]], 1);
        } else bkt[k] = -1;
    }
    __syncthreads();
    int hv = hist[t];
    sscan[t] = hv;
    __syncthreads();
    for (int off = 1; off < 256; off <<= 1) {
        int u = (t >= off) ? sscan[t - off] : 0;
        __syncthreads();
        sscan[t] += u;
        __syncthreads();
    }
    lstart[t] = sscan[t] - hv;
    lcur[t] = sscan[t] - hv;
    if (t == 0) lstart[256] = cnt;
    if (t < NBKT && hv > 0) gbase[t] = atomicAdd(&bcursor[t], hv);
    __syncthreads();
    #pragma unroll
    for (int k = 0; k < CTILE / 256; k++) {
        if (bkt[k] >= 0) {
            int p = atomicAdd(&lcur[bkt[k]], 1);
            buf[p] = ent[k];
        }
    }
    __syncthreads();
    for (int i = t; i < cnt; i += 256) {
        int lo = 0, hi = 255;
        while (lo < hi) {
            int mid = (lo + hi) >> 1;
            if (lstart[mid + 1] <= i) lo = mid + 1; else hi = mid;
        }
        se[gbase[lo] + (i - lstart[lo])] = buf[i];
    }
}

// D: fine sort within one bucket (in place) + emit offsets/deg/dinv
__global__ __launch_bounds__(256) void fine_sort(int2* __restrict__ se,
                                                 const int* __restrict__ bbase,
                                                 int* __restrict__ offsets,
                                                 int* __restrict__ deg,
                                                 float* __restrict__ dinv, int n) {
    __shared__ int2 buf[9216];           // 72 KB; bucket max ~8.6K entries
    __shared__ int hist[256], lstart[256], lcur[256];
    int t = threadIdx.x;
    int b = blockIdx.x;
    int node0 = b * 256;
    int nnodes = n - node0; if (nnodes > 256) nnodes = 256;
    int beg = bbase[b], end = bbase[b + 1];
    hist[t] = 0;
    __syncthreads();
    for (int i = beg + t; i < end; i += 256)
        atomicAdd(&hist[se[i].y >> 21], 1);
    __syncthreads();
    int hv = hist[t];
    lstart[t] = hv;
    __syncthreads();
    for (int off = 1; off < 256; off <<= 1) {
        int u = (t >= off) ? lstart[t - off] : 0;
        __syncthreads();
        lstart[t] += u;
        __syncthreads();
    }
    int ex = lstart[t] - hv;
    lcur[t] = ex;
    if (t < nnodes) {
        offsets[node0 + t] = beg + ex;
        deg[node0 + t] = hv;
        dinv[node0 + t] = 1.0f / fmaxf((float)hv, 1.0f);
    }
    __syncthreads();
    for (int i = beg + t; i < end; i += 256) {
        int2 v = se[i];
        int p = atomicAdd(&lcur[v.y >> 21], 1);
        buf[p] = make_int2(v.x, v.y & 0x1FFFFF);   // (src, eid)
    }
    __syncthreads();
    int cnt = end - beg;
    for (int i = t; i < cnt; i += 256)
        se[beg + i] = buf[i];
}

// 8-lane-per-row bf16 gather, 8 edges per wave-iteration.
// agg[node,0:64] = sum over srcs of tbl[src,0:64]; optionally fuse pos gather.
template <bool FUSE_POS>
__global__ void gather64_v2(const int* __restrict__ offsets, const int* __restrict__ deg,
                            const int2* __restrict__ se,
                            const unsigned short* __restrict__ tbl,
                            const float* __restrict__ pos,
                            float* __restrict__ agg, float* __restrict__ aggpos, int n) {
    int node = (int)((blockIdx.x * (unsigned)blockDim.x + threadIdx.x) >> 6);
    int lane = threadIdx.x & 63;
    if (node >= n) return;
    int q = lane >> 3, r = lane & 7;
    int beg = offsets[node];
    int cnt = deg[node];
    float acc[8];
    #pragma unroll
    for (int k = 0; k < 8; k++) acc[k] = 0.f;
    float p0 = 0.f, p1 = 0.f;
    for (int j = 0; j < cnt; j += 8) {
        int jj = j + q;
        if (jj < cnt) {
            int s = se[beg + jj].x;
            uint4 v = ((const uint4*)(tbl + (size_t)s * 64))[r];
            float lo, hi;
            bf2x2(v.x, lo, hi); acc[0] += lo; acc[1] += hi;
            bf2x2(v.y, lo, hi); acc[2] += lo; acc[3] += hi;
            bf2x2(v.z, lo, hi); acc[4] += lo; acc[5] += hi;
            bf2x2(v.w, lo, hi); acc[6] += lo; acc[7] += hi;
            if (FUSE_POS && r == 0) {
                float2 pv = ((const float2*)pos)[s];
                p0 += pv.x; p1 += pv.y;
            }
        }
    }
    // sum over the 8 q-groups (same r)
    #pragma unroll
    for (int off = 32; off >= 8; off >>= 1) {
        #pragma unroll
        for (int k = 0; k < 8; k++) acc[k] += __shfl_down(acc[k], off);
    }
    if (q == 0) {
        float4 a = make_float4(acc[0], acc[1], acc[2], acc[3]);
        float4 b = make_float4(acc[4], acc[5], acc[6], acc[7]);
        ((float4*)(agg + (size_t)node * 64))[2 * r]     = a;
        ((float4*)(agg + (size_t)node * 64))[2 * r + 1] = b;
    }
    if (FUSE_POS) {
        p0 += __shfl_down(p0, 32); p1 += __shfl_down(p1, 32);
        p0 += __shfl_down(p0, 16); p1 += __shfl_down(p1, 16);
        p0 += __shfl_down(p0, 8);  p1 += __shfl_down(p1, 8);
        if (lane == 0) {
            aggpos[(size_t)node * 2]     = p0;
            aggpos[(size_t)node * 2 + 1] = p1;
        }
    }
}

// h1 = relu([x|pos] @ W1r + dinv*[aggx|aggpos] @ W1n + b1), then fused
// z = bf16(h1 @ W2n). 8 nodes / 128 threads.
__global__ __launch_bounds__(128) void layer1(
        const float* __restrict__ x, const float* __restrict__ pos,
        const float* __restrict__ aggx, const float* __restrict__ aggpos,
        const float* __restrict__ dinv,
        const float* __restrict__ W1r, const float* __restrict__ W1n,
        const float* __restrict__ b1, const float* __restrict__ W2n,
        float* __restrict__ h1, unsigned short* __restrict__ zb) {
    __shared__ float sx[8 * 64], sax[8 * 64], sp[16], sap[16];
    __shared__ float sh1[8 * H1];
    int nb = blockIdx.x * 8;
    int h = threadIdx.x;
    for (int i = h; i < 8 * 64; i += 128) {
        sx[i]  = x[(size_t)nb * 64 + i];
        sax[i] = aggx[(size_t)nb * 64 + i];
    }
    if (h < 16) {
        sp[h]  = pos[(size_t)nb * 2 + h];
        sap[h] = aggpos[(size_t)nb * 2 + h];
    }
    __syncthreads();
    float accr[8], accn[8];
    #pragma unroll
    for (int n = 0; n < 8; n++) { accr[n] = 0.f; accn[n] = 0.f; }
    for (int k = 0; k < 64; k++) {
        float wr = W1r[k * H1 + h];
        float wn = W1n[k * H1 + h];
        #pragma unroll
        for (int n = 0; n < 8; n++) {
            accr[n] += sx[n * 64 + k] * wr;
            accn[n] += sax[n * 64 + k] * wn;
        }
    }
    #pragma unroll
    for (int k = 0; k < 2; k++) {
        float wr = W1r[(64 + k) * H1 + h];
        float wn = W1n[(64 + k) * H1 + h];
        #pragma unroll
        for (int n = 0; n < 8; n++) {
            accr[n] += sp[n * 2 + k] * wr;
            accn[n] += sap[n * 2 + k] * wn;
        }
    }
    float bias = b1[h];
    #pragma unroll
    for (int n = 0; n < 8; n++) {
        float v = fmaxf(accr[n] + dinv[nb + n] * accn[n] + bias, 0.f);
        h1[(size_t)(nb + n) * H1 + h] = v;
        sh1[n * H1 + h] = v;
    }
    __syncthreads();
    // z = h1 @ W2n for the 8 staged nodes: thread -> (o, n0), 4 nodes each
    int o = h & 63;
    int n0 = h >> 6;           // 0..1
    float za[4];
    #pragma unroll
    for (int m = 0; m < 4; m++) za[m] = 0.f;
    for (int k = 0; k < H1; k++) {
        float w = W2n[k * O_OUT + o];
        #pragma unroll
        for (int m = 0; m < 4; m++)
            za[m] += sh1[(n0 + 2 * m) * H1 + k] * w;   // broadcast read
    }
    #pragma unroll
    for (int m = 0; m < 4; m++)
        zb[(size_t)(nb + n0 + 2 * m) * O_OUT + o] = f2bf(za[m]);
}

// h2 = bf16(h1 @ W2r + dinv*aggz + b2)
__global__ __launch_bounds__(64) void layer2(
        const float* __restrict__ h1, const float* __restrict__ aggz,
        const float* __restrict__ dinv,
        const float* __restrict__ W2r, const float* __restrict__ b2,
        unsigned short* __restrict__ h2) {
    __shared__ float sh1[8 * H1];
    __shared__ float saz[8 * O_OUT];
    int nb = blockIdx.x * 8;
    int h = threadIdx.x;
    for (int i = h; i < 8 * H1; i += 64) sh1[i] = h1[(size_t)nb * H1 + i];
    for (int i = h; i < 8 * O_OUT; i += 64) saz[i] = aggz[(size_t)nb * O_OUT + i];
    __syncthreads();
    float acc[8];
    #pragma unroll
    for (int n = 0; n < 8; n++) acc[n] = 0.f;
    for (int k = 0; k < H1; k++) {
        float w = W2r[k * O_OUT + h];
        #pragma unroll
        for (int n = 0; n < 8; n++) acc[n] += sh1[n * H1 + k] * w;
    }
    float bias = b2[h];
    #pragma unroll
    for (int n = 0; n < 8; n++)
        h2[(size_t)(nb + n) * O_OUT + h] =
            f2bf(acc[n] + dinv[nb + n] * saz[n * O_OUT + h] + bias);
}

// out[eid] = dot(h2[src], h2[dst]); 8 lanes per row, 8 edges per iteration
__global__ void edge_out(const int* __restrict__ offsets, const int* __restrict__ deg,
                         const int2* __restrict__ se,
                         const unsigned short* __restrict__ h2,
                         float* __restrict__ out, int n) {
    int node = (int)((blockIdx.x * (unsigned)blockDim.x + threadIdx.x) >> 6);
    int lane = threadIdx.x & 63;
    if (node >= n) return;
    int q = lane >> 3, r = lane & 7;
    int beg = offsets[node];
    int cnt = deg[node];
    uint4 du = ((const uint4*)(h2 + (size_t)node * 64))[r];
    float d0, d1, d2, d3, d4, d5, d6, d7;
    bf2x2(du.x, d0, d1); bf2x2(du.y, d2, d3);
    bf2x2(du.z, d4, d5); bf2x2(du.w, d6, d7);
    for (int j = 0; j < cnt; j += 8) {
        int jj = j + q;
        if (jj < cnt) {
            int2 p = se[beg + jj];
            uint4 vu = ((const uint4*)(h2 + (size_t)p.x * 64))[r];
            float lo, hi, t;
            bf2x2(vu.x, lo, hi); t  = d0 * lo + d1 * hi;
            bf2x2(vu.y, lo, hi); t += d2 * lo + d3 * hi;
            bf2x2(vu.z, lo, hi); t += d4 * lo + d5 * hi;
            bf2x2(vu.w, lo, hi); t += d6 * lo + d7 * hi;
            t += __shfl_down(t, 4);
            t += __shfl_down(t, 2);
            t += __shfl_down(t, 1);
            if (r == 0) out[p.y] = t;
        }
    }
}

extern "C" void kernel_launch(void* const* d_in, const int* in_sizes, int n_in,
                              void* d_out, int out_size, void* d_ws, size_t ws_size,
                              hipStream_t stream) {
    const float* x   = (const float*)d_in[0];
    const float* pos = (const float*)d_in[1];
    const int*   ei  = (const int*)d_in[2];
    const float* W1r = (const float*)d_in[3];
    const float* W1n = (const float*)d_in[4];
    const float* b1  = (const float*)d_in[5];
    const float* W2r = (const float*)d_in[6];
    const float* W2n = (const float*)d_in[7];
    const float* b2  = (const float*)d_in[8];
    float* out = (float*)d_out;
    const int E = in_sizes[2] / 2;
    const int N = N_NODES;

    // ---- workspace layout ----
    int* bcount  = (int*)d_ws;                        // 200
    int* bbase   = bcount + 200;                      // 200 (197 used)
    int* bcursor = bbase + 200;                       // 200
    int* offsets = bcursor + 200;                     // N
    int* deg     = offsets + N;                       // N
    int2* se     = (int2*)(deg + N);                  // E pairs (8B-aligned)
    float* dinv   = (float*)(se + E);                 // N
    float* aggx   = dinv + N;                         // N*64
    float* aggpos = aggx + (size_t)N * 64;            // N*2
    float* h1     = aggpos + (size_t)N * 2;           // N*128
    float* aggz   = h1 + (size_t)N * H1;              // N*64
    unsigned short* xb = (unsigned short*)(aggz + (size_t)N * 64);  // N*64 bf16
    unsigned short* zb = xb + (size_t)N * 64;                       // N*64 bf16
    unsigned short* h2 = zb + (size_t)N * 64;                       // N*64 bf16

    hipMemsetAsync(bcount, 0, 200 * sizeof(int), stream);

    xcast<<<dim3((N * 16 + 255) / 256), dim3(256), 0, stream>>>(x, xb, N * 16);
    bucket_hist<<<dim3(512), dim3(256), 0, stream>>>(ei, E, bcount);
    bucket_scan<<<dim3(1), dim3(256), 0, stream>>>(bcount, bbase, bcursor);
    coarse_scatter<<<dim3((E + CTILE - 1) / CTILE), dim3(256), 0, stream>>>(ei, E, bcursor, se);
    fine_sort<<<dim3(NBKT), dim3(256), 0, stream>>>(se, bbase, offsets, deg, dinv, N);

    gather64_v2<true><<<dim3((N + 3) / 4), dim3(256), 0, stream>>>(
        offsets, deg, se, xb, pos, aggx, aggpos, N);
    layer1<<<dim3(N / 8), dim3(128), 0, stream>>>(
        x, pos, aggx, aggpos, dinv, W1r, W1n, b1, W2n, h1, zb);

    gather64_v2<false><<<dim3((N + 3) / 4), dim3(256), 0, stream>>>(
        offsets, deg, se, zb, nullptr, aggz, nullptr, N);
    layer2<<<dim3(N / 8), dim3(64), 0, stream>>>(h1, aggz, dinv, W2r, b2, h2);

    edge_out<<<dim3((N + 3) / 4), dim3(256), 0, stream>>>(offsets, deg, se, h2, out, N);
}

// Round 7
// 315.219 us; speedup vs baseline: 5.3690x; 1.2069x over previous
//
#include <hip/hip_runtime.h>

#define N_NODES 50000
#define H1 128
#define O_OUT 64
#define NBKT 196          // ceil(50000/256) dst buckets of 256 nodes
#define CTILE 4096        // edges per coarse-scatter tile
#define KA 160            // Abig padded K
#define AROW 80           // Abig row in uints (160 bf16)

typedef __attribute__((ext_vector_type(8))) short bf16x8;
typedef __attribute__((ext_vector_type(4))) float f32x4;

__device__ inline unsigned short f2bf(float f) {
    union { float f; unsigned u; } c; c.f = f;
    unsigned u = c.u;
    return (unsigned short)((u + 0x7FFF + ((u >> 16) & 1)) >> 16);  // RNE
}
__device__ inline unsigned pack2(float a, float b) {
    return (unsigned)f2bf(a) | ((unsigned)f2bf(b) << 16);
}
// unpack packed pair of bf16 (one uint) -> two floats
__device__ inline void bf2x2(unsigned u, float& lo, float& hi) {
    union { unsigned u; float f; } a, b;
    a.u = u << 16; b.u = u & 0xFFFF0000u;
    lo = a.f; hi = b.f;
}

// build Abig row: cols 0-63 = bf16(x), 128-129 = bf16(pos), 132-159 = 0
// (cols 64-127, 130-131 written by gather_x). 64 threads per node.
__global__ __launch_bounds__(256) void build_a(const float* __restrict__ x,
                                               const float* __restrict__ pos,
                                               unsigned int* __restrict__ Abig, int n) {
    int gid = blockIdx.x * 256 + threadIdx.x;
    int node = gid >> 6, t = gid & 63;
    if (node >= n) return;
    unsigned int* row = Abig + (size_t)node * AROW;
    if (t < 32) {
        float2 v = ((const float2*)x)[node * 32 + t];
        row[t] = pack2(v.x, v.y);
    } else if (t == 32) {
        float2 v = ((const float2*)pos)[node];
        row[64] = pack2(v.x, v.y);
    } else if (t < 47) {
        row[66 + (t - 33)] = 0;         // cols 132..159
    }
}

// transpose/cast weights: Wt1 [128 n][160 k], Wt2 [128 n][128 k]
__global__ __launch_bounds__(256) void wprep(const float* __restrict__ W1r,
                                             const float* __restrict__ W1n,
                                             const float* __restrict__ W2r,
                                             const float* __restrict__ W2n,
                                             unsigned short* __restrict__ Wt1,
                                             unsigned short* __restrict__ Wt2) {
    int t0 = blockIdx.x * 256 + threadIdx.x;
    int stride = gridDim.x * 256;
    for (int i = t0; i < 128 * KA; i += stride) {
        int n = i / KA, k = i % KA;
        float v;
        if (k < 64) v = W1r[k * H1 + n];
        else if (k < 128) v = W1n[(k - 64) * H1 + n];
        else if (k < 130) v = W1r[(64 + k - 128) * H1 + n];
        else if (k < 132) v = W1n[(64 + k - 130) * H1 + n];
        else v = 0.f;
        Wt1[i] = f2bf(v);
    }
    for (int i = t0; i < 128 * 128; i += stride) {
        int n = i / 128, k = i % 128;
        float v = (n < 64) ? W2r[k * 64 + n] : W2n[k * 64 + (n - 64)];
        Wt2[i] = f2bf(v);
    }
}

// A: coarse bucket histogram (bucket = dst>>8)
__global__ __launch_bounds__(256) void bucket_hist(const int* __restrict__ ei, int E,
                                                   int* __restrict__ bcount) {
    __shared__ int h[256];
    int t = threadIdx.x;
    h[t] = 0;
    __syncthreads();
    for (int e = blockIdx.x * 256 + t; e < E; e += gridDim.x * 256)
        atomicAdd(&h[ei[E + e] >> 8], 1);
    __syncthreads();
    if (t < NBKT && h[t]) atomicAdd(&bcount[t], h[t]);
}

// B: scan 196 bucket counts -> bucket_base[197] + cursor copy
__global__ __launch_bounds__(256) void bucket_scan(const int* __restrict__ bcount,
                                                   int* __restrict__ bbase,
                                                   int* __restrict__ bcursor) {
    __shared__ int s[256];
    int t = threadIdx.x;
    int v = (t < NBKT) ? bcount[t] : 0;
    s[t] = v;
    __syncthreads();
    for (int off = 1; off < 256; off <<= 1) {
        int u = (t >= off) ? s[t - off] : 0;
        __syncthreads();
        s[t] += u;
        __syncthreads();
    }
    if (t < NBKT) { bbase[t] = s[t] - v; bcursor[t] = s[t] - v; }
    if (t == 0) bbase[NBKT] = s[255];
}

// C: coarse scatter — tile of 4096 edges LDS-sorted by bucket
__global__ __launch_bounds__(256) void coarse_scatter(const int* __restrict__ ei, int E,
                                                      int* __restrict__ bcursor,
                                                      int2* __restrict__ se) {
    __shared__ int2 buf[CTILE];          // 32 KB
    __shared__ int hist[256], sscan[256], lstart[257], lcur[256], gbase[256];
    int t = threadIdx.x;
    int tile0 = blockIdx.x * CTILE;
    int cnt = E - tile0; if (cnt > CTILE) cnt = CTILE;
    hist[t] = 0;
    __syncthreads();
    int2 ent[CTILE / 256];
    int bkt[CTILE / 256];
    #pragma unroll
    for (int k = 0; k < CTILE / 256; k++) {
        int e = tile0 + k * 256 + t;
        if (e < E) {
            int src = ei[e];
            int dst = ei[E + e];
            bkt[k] = dst >> 8;
            ent[k] = make_int2(src, ((dst & 255) << 21) | e);
            atomicAdd(&hist[bkt[k]], 1);
        } else bkt[k] = -1;
    }
    __syncthreads();
    int hv = hist[t];
    sscan[t] = hv;
    __syncthreads();
    for (int off = 1; off < 256; off <<= 1) {
        int u = (t >= off) ? sscan[t - off] : 0;
        __syncthreads();
        sscan[t] += u;
        __syncthreads();
    }
    lstart[t] = sscan[t] - hv;
    lcur[t] = sscan[t] - hv;
    if (t == 0) lstart[256] = cnt;
    if (t < NBKT && hv > 0) gbase[t] = atomicAdd(&bcursor[t], hv);
    __syncthreads();
    #pragma unroll
    for (int k = 0; k < CTILE / 256; k++) {
        if (bkt[k] >= 0) {
            int p = atomicAdd(&lcur[bkt[k]], 1);
            buf[p] = ent[k];
        }
    }
    __syncthreads();
    for (int i = t; i < cnt; i += 256) {
        int lo = 0, hi = 255;
        while (lo < hi) {
            int mid = (lo + hi) >> 1;
            if (lstart[mid + 1] <= i) lo = mid + 1; else hi = mid;
        }
        se[gbase[lo] + (i - lstart[lo])] = buf[i];
    }
}

// D: fine sort within one bucket (in place) + emit offsets/deg
__global__ __launch_bounds__(256) void fine_sort(int2* __restrict__ se,
                                                 const int* __restrict__ bbase,
                                                 int* __restrict__ offsets,
                                                 int* __restrict__ deg, int n) {
    __shared__ int2 buf[9216];           // 72 KB; bucket max ~8.6K entries
    __shared__ int hist[256], lstart[256], lcur[256];
    int t = threadIdx.x;
    int b = blockIdx.x;
    int node0 = b * 256;
    int nnodes = n - node0; if (nnodes > 256) nnodes = 256;
    int beg = bbase[b], end = bbase[b + 1];
    hist[t] = 0;
    __syncthreads();
    for (int i = beg + t; i < end; i += 256)
        atomicAdd(&hist[se[i].y >> 21], 1);
    __syncthreads();
    int hv = hist[t];
    lstart[t] = hv;
    __syncthreads();
    for (int off = 1; off < 256; off <<= 1) {
        int u = (t >= off) ? lstart[t - off] : 0;
        __syncthreads();
        lstart[t] += u;
        __syncthreads();
    }
    int ex = lstart[t] - hv;
    lcur[t] = ex;
    if (t < nnodes) {
        offsets[node0 + t] = beg + ex;
        deg[node0 + t] = hv;
    }
    __syncthreads();
    for (int i = beg + t; i < end; i += 256) {
        int2 v = se[i];
        int p = atomicAdd(&lcur[v.y >> 21], 1);
        buf[p] = make_int2(v.x, v.y & 0x1FFFFF);   // (src, eid)
    }
    __syncthreads();
    int cnt = end - beg;
    for (int i = t; i < cnt; i += 256)
        se[beg + i] = buf[i];
}

// gather x+pos from Abig rows; write dinv-scaled bf16 aggregates back into
// Abig cols 64-127 (uint4) and 130-131. 8 lanes/row, 8 edges per iteration.
__global__ void gather_x(const int* __restrict__ offsets, const int* __restrict__ deg,
                         const int2* __restrict__ se,
                         const float* __restrict__ pos,
                         unsigned int* __restrict__ Abig, int n) {
    int node = (int)((blockIdx.x * (unsigned)blockDim.x + threadIdx.x) >> 6);
    int lane = threadIdx.x & 63;
    if (node >= n) return;
    int q = lane >> 3, r = lane & 7;
    int beg = offsets[node];
    int cnt = deg[node];
    float acc[8];
    #pragma unroll
    for (int k = 0; k < 8; k++) acc[k] = 0.f;
    float p0 = 0.f, p1 = 0.f;
    for (int j = 0; j < cnt; j += 8) {
        int jj = j + q;
        if (jj < cnt) {
            int s = se[beg + jj].x;
            uint4 v = ((const uint4*)(Abig + (size_t)s * AROW))[r];   // x cols 8r..8r+7
            float lo, hi;
            bf2x2(v.x, lo, hi); acc[0] += lo; acc[1] += hi;
            bf2x2(v.y, lo, hi); acc[2] += lo; acc[3] += hi;
            bf2x2(v.z, lo, hi); acc[4] += lo; acc[5] += hi;
            bf2x2(v.w, lo, hi); acc[6] += lo; acc[7] += hi;
            if (r == 0) {
                float2 pv = ((const float2*)pos)[s];
                p0 += pv.x; p1 += pv.y;
            }
        }
    }
    #pragma unroll
    for (int off = 32; off >= 8; off >>= 1) {
        #pragma unroll
        for (int k = 0; k < 8; k++) acc[k] += __shfl_down(acc[k], off);
    }
    float dinv = 1.0f / fmaxf((float)cnt, 1.0f);
    if (q == 0) {
        uint4 o;
        o.x = pack2(acc[0] * dinv, acc[1] * dinv);
        o.y = pack2(acc[2] * dinv, acc[3] * dinv);
        o.z = pack2(acc[4] * dinv, acc[5] * dinv);
        o.w = pack2(acc[6] * dinv, acc[7] * dinv);
        ((uint4*)(Abig + (size_t)node * AROW + 32))[r] = o;   // cols 64+8r..71+8r
    }
    p0 += __shfl_down(p0, 32); p1 += __shfl_down(p1, 32);
    p0 += __shfl_down(p0, 16); p1 += __shfl_down(p1, 16);
    p0 += __shfl_down(p0, 8);  p1 += __shfl_down(p1, 8);
    if (lane == 0)
        Abig[(size_t)node * AROW + 65] = pack2(p0 * dinv, p1 * dinv);  // cols 130-131
}

// MFMA GEMM 1: h1 = relu(Abig[M x 160] @ Wt1^T + b1) -> bf16 [M x 128]
__global__ __launch_bounds__(256) void gemm1(const unsigned short* __restrict__ A,
                                             const unsigned short* __restrict__ Wt,
                                             const float* __restrict__ b1,
                                             unsigned short* __restrict__ h1, int M) {
    const int K = KA, LDSK = 168;         // pad: 16B-aligned rows, ~2-way banks
    __shared__ unsigned short lw[128 * LDSK];   // 43 KB
    int t = threadIdx.x;
    for (int idx = t; idx < 128 * (K / 8); idx += 256) {
        int row = idx / (K / 8), kc = idx % (K / 8);
        *(uint4*)&lw[row * LDSK + kc * 8] = *(const uint4*)&Wt[row * K + kc * 8];
    }
    __syncthreads();
    int wave = t >> 6, lane = t & 63;
    int nq = lane & 15, q = lane >> 4;
    int m0 = blockIdx.x * 64 + wave * 16;
    int arow = m0 + nq;
    if (arow >= M) arow = M - 1;
    f32x4 acc[8];
    #pragma unroll
    for (int i = 0; i < 8; i++) acc[i] = (f32x4){0.f, 0.f, 0.f, 0.f};
    for (int ks = 0; ks < K; ks += 32) {
        bf16x8 a = *(const bf16x8*)&A[(size_t)arow * K + ks + q * 8];
        #pragma unroll
        for (int nt = 0; nt < 8; nt++) {
            bf16x8 b = *(const bf16x8*)&lw[(nt * 16 + nq) * LDSK + ks + q * 8];
            acc[nt] = __builtin_amdgcn_mfma_f32_16x16x32_bf16(a, b, acc[nt], 0, 0, 0);
        }
    }
    int crow = m0 + q * 4;
    #pragma unroll
    for (int nt = 0; nt < 8; nt++) {
        int col = nt * 16 + nq;
        float bias = b1[col];
        #pragma unroll
        for (int i = 0; i < 4; i++) {
            int rr = crow + i;
            if (rr < M)
                h1[(size_t)rr * H1 + col] = f2bf(fmaxf(acc[nt][i] + bias, 0.f));
        }
    }
}

// MFMA GEMM 2: C = h1[M x 128] @ [W2r|W2n]; cols 0-63 -> h2part fp32,
// cols 64-127 -> zb bf16 table
__global__ __launch_bounds__(256) void gemm2(const unsigned short* __restrict__ A,
                                             const unsigned short* __restrict__ Wt,
                                             float* __restrict__ h2part,
                                             unsigned short* __restrict__ zb, int M) {
    const int K = 128, LDSK = 136;
    __shared__ unsigned short lw[128 * LDSK];   // 34 KB
    int t = threadIdx.x;
    for (int idx = t; idx < 128 * (K / 8); idx += 256) {
        int row = idx / (K / 8), kc = idx % (K / 8);
        *(uint4*)&lw[row * LDSK + kc * 8] = *(const uint4*)&Wt[row * K + kc * 8];
    }
    __syncthreads();
    int wave = t >> 6, lane = t & 63;
    int nq = lane & 15, q = lane >> 4;
    int m0 = blockIdx.x * 64 + wave * 16;
    int arow = m0 + nq;
    if (arow >= M) arow = M - 1;
    f32x4 acc[8];
    #pragma unroll
    for (int i = 0; i < 8; i++) acc[i] = (f32x4){0.f, 0.f, 0.f, 0.f};
    for (int ks = 0; ks < K; ks += 32) {
        bf16x8 a = *(const bf16x8*)&A[(size_t)arow * K + ks + q * 8];
        #pragma unroll
        for (int nt = 0; nt < 8; nt++) {
            bf16x8 b = *(const bf16x8*)&lw[(nt * 16 + nq) * LDSK + ks + q * 8];
            acc[nt] = __builtin_amdgcn_mfma_f32_16x16x32_bf16(a, b, acc[nt], 0, 0, 0);
        }
    }
    int crow = m0 + q * 4;
    #pragma unroll
    for (int nt = 0; nt < 8; nt++) {
        int col = nt * 16 + nq;
        #pragma unroll
        for (int i = 0; i < 4; i++) {
            int rr = crow + i;
            if (rr < M) {
                if (col < 64) h2part[(size_t)rr * 64 + col] = acc[nt][i];
                else          zb[(size_t)rr * 64 + (col - 64)] = f2bf(acc[nt][i]);
            }
        }
    }
}

// gather z (bf16 rows) + fused epilogue: h2 = bf16(h2part + dinv*aggz + b2)
__global__ void gather_z(const int* __restrict__ offsets, const int* __restrict__ deg,
                         const int2* __restrict__ se,
                         const unsigned short* __restrict__ zb,
                         const float* __restrict__ h2part,
                         const float* __restrict__ b2,
                         unsigned short* __restrict__ h2, int n) {
    int node = (int)((blockIdx.x * (unsigned)blockDim.x + threadIdx.x) >> 6);
    int lane = threadIdx.x & 63;
    if (node >= n) return;
    int q = lane >> 3, r = lane & 7;
    int beg = offsets[node];
    int cnt = deg[node];
    float acc[8];
    #pragma unroll
    for (int k = 0; k < 8; k++) acc[k] = 0.f;
    for (int j = 0; j < cnt; j += 8) {
        int jj = j + q;
        if (jj < cnt) {
            int s = se[beg + jj].x;
            uint4 v = ((const uint4*)(zb + (size_t)s * 64))[r];
            float lo, hi;
            bf2x2(v.x, lo, hi); acc[0] += lo; acc[1] += hi;
            bf2x2(v.y, lo, hi); acc[2] += lo; acc[3] += hi;
            bf2x2(v.z, lo, hi); acc[4] += lo; acc[5] += hi;
            bf2x2(v.w, lo, hi); acc[6] += lo; acc[7] += hi;
        }
    }
    #pragma unroll
    for (int off = 32; off >= 8; off >>= 1) {
        #pragma unroll
        for (int k = 0; k < 8; k++) acc[k] += __shfl_down(acc[k], off);
    }
    if (q == 0) {
        float dinv = 1.0f / fmaxf((float)cnt, 1.0f);
        float4 ha = ((const float4*)(h2part + (size_t)node * 64))[2 * r];
        float4 hb = ((const float4*)(h2part + (size_t)node * 64))[2 * r + 1];
        float4 ba = ((const float4*)b2)[2 * r];
        float4 bb = ((const float4*)b2)[2 * r + 1];
        uint4 o;
        o.x = pack2(ha.x + dinv * acc[0] + ba.x, ha.y + dinv * acc[1] + ba.y);
        o.y = pack2(ha.z + dinv * acc[2] + ba.z, ha.w + dinv * acc[3] + ba.w);
        o.z = pack2(hb.x + dinv * acc[4] + bb.x, hb.y + dinv * acc[5] + bb.y);
        o.w = pack2(hb.z + dinv * acc[6] + bb.z, hb.w + dinv * acc[7] + bb.w);
        ((uint4*)(h2 + (size_t)node * 64))[r] = o;
    }
}

// out[eid] = dot(h2[src], h2[dst]); 8 lanes per row, 8 edges per iteration
__global__ void edge_out(const int* __restrict__ offsets, const int* __restrict__ deg,
                         const int2* __restrict__ se,
                         const unsigned short* __restrict__ h2,
                         float* __restrict__ out, int n) {
    int node = (int)((blockIdx.x * (unsigned)blockDim.x + threadIdx.x) >> 6);
    int lane = threadIdx.x & 63;
    if (node >= n) return;
    int q = lane >> 3, r = lane & 7;
    int beg = offsets[node];
    int cnt = deg[node];
    uint4 du = ((const uint4*)(h2 + (size_t)node * 64))[r];
    float d0, d1, d2, d3, d4, d5, d6, d7;
    bf2x2(du.x, d0, d1); bf2x2(du.y, d2, d3);
    bf2x2(du.z, d4, d5); bf2x2(du.w, d6, d7);
    for (int j = 0; j < cnt; j += 8) {
        int jj = j + q;
        if (jj < cnt) {
            int2 p = se[beg + jj];
            uint4 vu = ((const uint4*)(h2 + (size_t)p.x * 64))[r];
            float lo, hi, t;
            bf2x2(vu.x, lo, hi); t  = d0 * lo + d1 * hi;
            bf2x2(vu.y, lo, hi); t += d2 * lo + d3 * hi;
            bf2x2(vu.z, lo, hi); t += d4 * lo + d5 * hi;
            bf2x2(vu.w, lo, hi); t += d6 * lo + d7 * hi;
            t += __shfl_down(t, 4);
            t += __shfl_down(t, 2);
            t += __shfl_down(t, 1);
            if (r == 0) out[p.y] = t;
        }
    }
}

extern "C" void kernel_launch(void* const* d_in, const int* in_sizes, int n_in,
                              void* d_out, int out_size, void* d_ws, size_t ws_size,
                              hipStream_t stream) {
    const float* x   = (const float*)d_in[0];
    const float* pos = (const float*)d_in[1];
    const int*   ei  = (const int*)d_in[2];
    const float* W1r = (const float*)d_in[3];
    const float* W1n = (const float*)d_in[4];
    const float* b1  = (const float*)d_in[5];
    const float* W2r = (const float*)d_in[6];
    const float* W2n = (const float*)d_in[7];
    const float* b2  = (const float*)d_in[8];
    float* out = (float*)d_out;
    const int E = in_sizes[2] / 2;
    const int N = N_NODES;

    // ---- workspace layout (16B-aligned blocks first) ----
    unsigned short* Abig  = (unsigned short*)d_ws;           // N*160 bf16 (16 MB)
    unsigned short* h1    = Abig + (size_t)N * KA;           // N*128 bf16
    unsigned short* zb    = h1 + (size_t)N * H1;             // N*64 bf16
    unsigned short* h2    = zb + (size_t)N * 64;             // N*64 bf16
    float* h2part         = (float*)(h2 + (size_t)N * 64);   // N*64 fp32
    unsigned short* Wt1   = (unsigned short*)(h2part + (size_t)N * 64);  // 128*160
    unsigned short* Wt2   = Wt1 + 128 * KA;                  // 128*128
    int* bcount  = (int*)(Wt2 + 128 * 128);                  // 256
    int* bbase   = bcount + 256;                             // 256
    int* bcursor = bbase + 256;                              // 256
    int* offsets = bcursor + 256;                            // N
    int* deg     = offsets + N;                              // N
    int2* se     = (int2*)(deg + N);                         // E pairs

    hipMemsetAsync(bcount, 0, 256 * sizeof(int), stream);

    wprep<<<dim3(16), dim3(256), 0, stream>>>(W1r, W1n, W2r, W2n, Wt1, Wt2);
    build_a<<<dim3((N * 64 + 255) / 256), dim3(256), 0, stream>>>(
        x, pos, (unsigned int*)Abig, N);

    bucket_hist<<<dim3(512), dim3(256), 0, stream>>>(ei, E, bcount);
    bucket_scan<<<dim3(1), dim3(256), 0, stream>>>(bcount, bbase, bcursor);
    coarse_scatter<<<dim3((E + CTILE - 1) / CTILE), dim3(256), 0, stream>>>(ei, E, bcursor, se);
    fine_sort<<<dim3(NBKT), dim3(256), 0, stream>>>(se, bbase, offsets, deg, N);

    gather_x<<<dim3((N + 3) / 4), dim3(256), 0, stream>>>(
        offsets, deg, se, pos, (unsigned int*)Abig, N);
    gemm1<<<dim3((N + 63) / 64), dim3(256), 0, stream>>>(Abig, Wt1, b1, h1, N);
    gemm2<<<dim3((N + 63) / 64), dim3(256), 0, stream>>>(h1, Wt2, h2part, zb, N);
    gather_z<<<dim3((N + 3) / 4), dim3(256), 0, stream>>>(
        offsets, deg, se, zb, h2part, b2, h2, N);
    edge_out<<<dim3((N + 3) / 4), dim3(256), 0, stream>>>(offsets, deg, se, h2, out, N);
}

// Round 8
// 309.221 us; speedup vs baseline: 5.4731x; 1.0194x over previous
//
#include <hip/hip_runtime.h>

#define N_NODES 50000
#define H1 128
#define O_OUT 64
#define NBKT 196          // ceil(50000/256) dst buckets of 256 nodes
#define CTILE 4096        // edges per coarse-scatter tile
#define KA 160            // Abig padded K
#define AROW 80           // Abig row in uints (160 bf16)

typedef __attribute__((ext_vector_type(8))) short bf16x8;
typedef __attribute__((ext_vector_type(4))) float f32x4;

__device__ inline unsigned short f2bf(float f) {
    union { float f; unsigned u; } c; c.f = f;
    unsigned u = c.u;
    return (unsigned short)((u + 0x7FFF + ((u >> 16) & 1)) >> 16);  // RNE
}
__device__ inline unsigned pack2(float a, float b) {
    return (unsigned)f2bf(a) | ((unsigned)f2bf(b) << 16);
}
// unpack packed pair of bf16 (one uint) -> two floats
__device__ inline void bf2x2(unsigned u, float& lo, float& hi) {
    union { unsigned u; float f; } a, b;
    a.u = u << 16; b.u = u & 0xFFFF0000u;
    lo = a.f; hi = b.f;
}

// build Abig row: cols 0-63 = bf16(x), 128-129 = bf16(pos), 132-159 = 0
__global__ __launch_bounds__(256) void build_a(const float* __restrict__ x,
                                               const float* __restrict__ pos,
                                               unsigned int* __restrict__ Abig, int n) {
    int gid = blockIdx.x * 256 + threadIdx.x;
    int node = gid >> 6, t = gid & 63;
    if (node >= n) return;
    unsigned int* row = Abig + (size_t)node * AROW;
    if (t < 32) {
        float2 v = ((const float2*)x)[node * 32 + t];
        row[t] = pack2(v.x, v.y);
    } else if (t == 32) {
        float2 v = ((const float2*)pos)[node];
        row[64] = pack2(v.x, v.y);
    } else if (t < 47) {
        row[66 + (t - 33)] = 0;         // cols 132..159
    }
}

// transpose/cast weights: Wt1 [128 n][160 k], Wt2 [128 n][128 k]
__global__ __launch_bounds__(256) void wprep(const float* __restrict__ W1r,
                                             const float* __restrict__ W1n,
                                             const float* __restrict__ W2r,
                                             const float* __restrict__ W2n,
                                             unsigned short* __restrict__ Wt1,
                                             unsigned short* __restrict__ Wt2) {
    int t0 = blockIdx.x * 256 + threadIdx.x;
    int stride = gridDim.x * 256;
    for (int i = t0; i < 128 * KA; i += stride) {
        int n = i / KA, k = i % KA;
        float v;
        if (k < 64) v = W1r[k * H1 + n];
        else if (k < 128) v = W1n[(k - 64) * H1 + n];
        else if (k < 130) v = W1r[(64 + k - 128) * H1 + n];
        else if (k < 132) v = W1n[(64 + k - 130) * H1 + n];
        else v = 0.f;
        Wt1[i] = f2bf(v);
    }
    for (int i = t0; i < 128 * 128; i += stride) {
        int n = i / 128, k = i % 128;
        float v = (n < 64) ? W2r[k * 64 + n] : W2n[k * 64 + (n - 64)];
        Wt2[i] = f2bf(v);
    }
}

// A: coarse bucket histogram (bucket = dst>>8)
__global__ __launch_bounds__(256) void bucket_hist(const int* __restrict__ ei, int E,
                                                   int* __restrict__ bcount) {
    __shared__ int h[256];
    int t = threadIdx.x;
    h[t] = 0;
    __syncthreads();
    for (int e = blockIdx.x * 256 + t; e < E; e += gridDim.x * 256)
        atomicAdd(&h[ei[E + e] >> 8], 1);
    __syncthreads();
    if (t < NBKT && h[t]) atomicAdd(&bcount[t], h[t]);
}

// B: scan 196 bucket counts -> bucket_base[197] + cursor copy
__global__ __launch_bounds__(256) void bucket_scan(const int* __restrict__ bcount,
                                                   int* __restrict__ bbase,
                                                   int* __restrict__ bcursor) {
    __shared__ int s[256];
    int t = threadIdx.x;
    int v = (t < NBKT) ? bcount[t] : 0;
    s[t] = v;
    __syncthreads();
    for (int off = 1; off < 256; off <<= 1) {
        int u = (t >= off) ? s[t - off] : 0;
        __syncthreads();
        s[t] += u;
        __syncthreads();
    }
    if (t < NBKT) { bbase[t] = s[t] - v; bcursor[t] = s[t] - v; }
    if (t == 0) bbase[NBKT] = s[255];
}

// C: coarse scatter — tile of 4096 edges LDS-sorted by bucket
__global__ __launch_bounds__(256) void coarse_scatter(const int* __restrict__ ei, int E,
                                                      int* __restrict__ bcursor,
                                                      int2* __restrict__ se) {
    __shared__ int2 buf[CTILE];          // 32 KB
    __shared__ int hist[256], sscan[256], lstart[257], lcur[256], gbase[256];
    int t = threadIdx.x;
    int tile0 = blockIdx.x * CTILE;
    int cnt = E - tile0; if (cnt > CTILE) cnt = CTILE;
    hist[t] = 0;
    __syncthreads();
    int2 ent[CTILE / 256];
    int bkt[CTILE / 256];
    #pragma unroll
    for (int k = 0; k < CTILE / 256; k++) {
        int e = tile0 + k * 256 + t;
        if (e < E) {
            int src = ei[e];
            int dst = ei[E + e];
            bkt[k] = dst >> 8;
            ent[k] = make_int2(src, ((dst & 255) << 21) | e);
            atomicAdd(&hist[bkt[k]], 1);
        } else bkt[k] = -1;
    }
    __syncthreads();
    int hv = hist[t];
    sscan[t] = hv;
    __syncthreads();
    for (int off = 1; off < 256; off <<= 1) {
        int u = (t >= off) ? sscan[t - off] : 0;
        __syncthreads();
        sscan[t] += u;
        __syncthreads();
    }
    lstart[t] = sscan[t] - hv;
    lcur[t] = sscan[t] - hv;
    if (t == 0) lstart[256] = cnt;
    if (t < NBKT && hv > 0) gbase[t] = atomicAdd(&bcursor[t], hv);
    __syncthreads();
    #pragma unroll
    for (int k = 0; k < CTILE / 256; k++) {
        if (bkt[k] >= 0) {
            int p = atomicAdd(&lcur[bkt[k]], 1);
            buf[p] = ent[k];
        }
    }
    __syncthreads();
    for (int i = t; i < cnt; i += 256) {
        int lo = 0, hi = 255;
        while (lo < hi) {
            int mid = (lo + hi) >> 1;
            if (lstart[mid + 1] <= i) lo = mid + 1; else hi = mid;
        }
        se[gbase[lo] + (i - lstart[lo])] = buf[i];
    }
}

// D: fine sort within one bucket (in place) + emit offsets/deg
__global__ __launch_bounds__(256) void fine_sort(int2* __restrict__ se,
                                                 const int* __restrict__ bbase,
                                                 int* __restrict__ offsets,
                                                 int* __restrict__ deg, int n) {
    __shared__ int2 buf[9216];           // 72 KB; bucket max ~8.6K entries
    __shared__ int hist[256], lstart[256], lcur[256];
    int t = threadIdx.x;
    int b = blockIdx.x;
    int node0 = b * 256;
    int nnodes = n - node0; if (nnodes > 256) nnodes = 256;
    int beg = bbase[b], end = bbase[b + 1];
    hist[t] = 0;
    __syncthreads();
    for (int i = beg + t; i < end; i += 256)
        atomicAdd(&hist[se[i].y >> 21], 1);
    __syncthreads();
    int hv = hist[t];
    lstart[t] = hv;
    __syncthreads();
    for (int off = 1; off < 256; off <<= 1) {
        int u = (t >= off) ? lstart[t - off] : 0;
        __syncthreads();
        lstart[t] += u;
        __syncthreads();
    }
    int ex = lstart[t] - hv;
    lcur[t] = ex;
    if (t < nnodes) {
        offsets[node0 + t] = beg + ex;
        deg[node0 + t] = hv;
    }
    __syncthreads();
    for (int i = beg + t; i < end; i += 256) {
        int2 v = se[i];
        int p = atomicAdd(&lcur[v.y >> 21], 1);
        buf[p] = make_int2(v.x, v.y & 0x1FFFFF);   // (src, eid)
    }
    __syncthreads();
    int cnt = end - beg;
    for (int i = t; i < cnt; i += 256)
        se[beg + i] = buf[i];
}

// gather x+pos from Abig rows; write dinv-scaled bf16 aggregates back into
// Abig cols 64-127 / 130-131. 8 lanes/row, 16 edges per iteration (unroll 2).
__global__ void gather_x(const int* __restrict__ offsets, const int* __restrict__ deg,
                         const int2* __restrict__ se,
                         const float* __restrict__ pos,
                         unsigned int* __restrict__ Abig, int n) {
    int node = (int)((blockIdx.x * (unsigned)blockDim.x + threadIdx.x) >> 6);
    int lane = threadIdx.x & 63;
    if (node >= n) return;
    int q = lane >> 3, r = lane & 7;
    int beg = offsets[node];
    int cnt = deg[node];
    float acc[8];
    #pragma unroll
    for (int k = 0; k < 8; k++) acc[k] = 0.f;
    float p0 = 0.f, p1 = 0.f;
    for (int j = 0; j < cnt; j += 16) {
        int j0 = j + q, j1 = j + 8 + q;
        if (j0 < cnt) {
            int s = se[beg + j0].x;
            uint4 v = ((const uint4*)(Abig + (size_t)s * AROW))[r];
            float lo, hi;
            bf2x2(v.x, lo, hi); acc[0] += lo; acc[1] += hi;
            bf2x2(v.y, lo, hi); acc[2] += lo; acc[3] += hi;
            bf2x2(v.z, lo, hi); acc[4] += lo; acc[5] += hi;
            bf2x2(v.w, lo, hi); acc[6] += lo; acc[7] += hi;
            if (r == 0) {
                float2 pv = ((const float2*)pos)[s];
                p0 += pv.x; p1 += pv.y;
            }
        }
        if (j1 < cnt) {
            int s = se[beg + j1].x;
            uint4 v = ((const uint4*)(Abig + (size_t)s * AROW))[r];
            float lo, hi;
            bf2x2(v.x, lo, hi); acc[0] += lo; acc[1] += hi;
            bf2x2(v.y, lo, hi); acc[2] += lo; acc[3] += hi;
            bf2x2(v.z, lo, hi); acc[4] += lo; acc[5] += hi;
            bf2x2(v.w, lo, hi); acc[6] += lo; acc[7] += hi;
            if (r == 0) {
                float2 pv = ((const float2*)pos)[s];
                p0 += pv.x; p1 += pv.y;
            }
        }
    }
    #pragma unroll
    for (int off = 32; off >= 8; off >>= 1) {
        #pragma unroll
        for (int k = 0; k < 8; k++) acc[k] += __shfl_down(acc[k], off);
    }
    float dinv = 1.0f / fmaxf((float)cnt, 1.0f);
    if (q == 0) {
        uint4 o;
        o.x = pack2(acc[0] * dinv, acc[1] * dinv);
        o.y = pack2(acc[2] * dinv, acc[3] * dinv);
        o.z = pack2(acc[4] * dinv, acc[5] * dinv);
        o.w = pack2(acc[6] * dinv, acc[7] * dinv);
        ((uint4*)(Abig + (size_t)node * AROW + 32))[r] = o;
    }
    p0 += __shfl_down(p0, 32); p1 += __shfl_down(p1, 32);
    p0 += __shfl_down(p0, 16); p1 += __shfl_down(p1, 16);
    p0 += __shfl_down(p0, 8);  p1 += __shfl_down(p1, 8);
    if (lane == 0)
        Abig[(size_t)node * AROW + 65] = pack2(p0 * dinv, p1 * dinv);
}

// MFMA GEMM 1: h1 = relu(Abig[M x 160] @ Wt1^T + b1) -> bf16 [M x 128]
__global__ __launch_bounds__(256) void gemm1(const unsigned short* __restrict__ A,
                                             const unsigned short* __restrict__ Wt,
                                             const float* __restrict__ b1,
                                             unsigned short* __restrict__ h1, int M) {
    const int K = KA, LDSK = 168;
    __shared__ unsigned short lw[128 * LDSK];   // 43 KB
    int t = threadIdx.x;
    for (int idx = t; idx < 128 * (K / 8); idx += 256) {
        int row = idx / (K / 8), kc = idx % (K / 8);
        *(uint4*)&lw[row * LDSK + kc * 8] = *(const uint4*)&Wt[row * K + kc * 8];
    }
    __syncthreads();
    int wave = t >> 6, lane = t & 63;
    int nq = lane & 15, q = lane >> 4;
    int m0 = blockIdx.x * 64 + wave * 16;
    int arow = m0 + nq;
    if (arow >= M) arow = M - 1;
    f32x4 acc[8];
    #pragma unroll
    for (int i = 0; i < 8; i++) acc[i] = (f32x4){0.f, 0.f, 0.f, 0.f};
    for (int ks = 0; ks < K; ks += 32) {
        bf16x8 a = *(const bf16x8*)&A[(size_t)arow * K + ks + q * 8];
        #pragma unroll
        for (int nt = 0; nt < 8; nt++) {
            bf16x8 b = *(const bf16x8*)&lw[(nt * 16 + nq) * LDSK + ks + q * 8];
            acc[nt] = __builtin_amdgcn_mfma_f32_16x16x32_bf16(a, b, acc[nt], 0, 0, 0);
        }
    }
    int crow = m0 + q * 4;
    #pragma unroll
    for (int nt = 0; nt < 8; nt++) {
        int col = nt * 16 + nq;
        float bias = b1[col];
        #pragma unroll
        for (int i = 0; i < 4; i++) {
            int rr = crow + i;
            if (rr < M)
                h1[(size_t)rr * H1 + col] = f2bf(fmaxf(acc[nt][i] + bias, 0.f));
        }
    }
}

// MFMA GEMM 2: C = h1[M x 128] @ [W2r|W2n]; cols 0-63 -> h2part bf16,
// cols 64-127 -> zb bf16 table
__global__ __launch_bounds__(256) void gemm2(const unsigned short* __restrict__ A,
                                             const unsigned short* __restrict__ Wt,
                                             unsigned short* __restrict__ h2part,
                                             unsigned short* __restrict__ zb, int M) {
    const int K = 128, LDSK = 136;
    __shared__ unsigned short lw[128 * LDSK];   // 34 KB
    int t = threadIdx.x;
    for (int idx = t; idx < 128 * (K / 8); idx += 256) {
        int row = idx / (K / 8), kc = idx % (K / 8);
        *(uint4*)&lw[row * LDSK + kc * 8] = *(const uint4*)&Wt[row * K + kc * 8];
    }
    __syncthreads();
    int wave = t >> 6, lane = t & 63;
    int nq = lane & 15, q = lane >> 4;
    int m0 = blockIdx.x * 64 + wave * 16;
    int arow = m0 + nq;
    if (arow >= M) arow = M - 1;
    f32x4 acc[8];
    #pragma unroll
    for (int i = 0; i < 8; i++) acc[i] = (f32x4){0.f, 0.f, 0.f, 0.f};
    for (int ks = 0; ks < K; ks += 32) {
        bf16x8 a = *(const bf16x8*)&A[(size_t)arow * K + ks + q * 8];
        #pragma unroll
        for (int nt = 0; nt < 8; nt++) {
            bf16x8 b = *(const bf16x8*)&lw[(nt * 16 + nq) * LDSK + ks + q * 8];
            acc[nt] = __builtin_amdgcn_mfma_f32_16x16x32_bf16(a, b, acc[nt], 0, 0, 0);
        }
    }
    int crow = m0 + q * 4;
    #pragma unroll
    for (int nt = 0; nt < 8; nt++) {
        int col = nt * 16 + nq;
        #pragma unroll
        for (int i = 0; i < 4; i++) {
            int rr = crow + i;
            if (rr < M) {
                if (col < 64) h2part[(size_t)rr * 64 + col] = f2bf(acc[nt][i]);
                else          zb[(size_t)rr * 64 + (col - 64)] = f2bf(acc[nt][i]);
            }
        }
    }
}

// gather z (bf16 rows, unroll 2) + fused epilogue:
// h2 = bf16(h2part + dinv*aggz + b2)
__global__ void gather_z(const int* __restrict__ offsets, const int* __restrict__ deg,
                         const int2* __restrict__ se,
                         const unsigned short* __restrict__ zb,
                         const unsigned short* __restrict__ h2part,
                         const float* __restrict__ b2,
                         unsigned short* __restrict__ h2, int n) {
    int node = (int)((blockIdx.x * (unsigned)blockDim.x + threadIdx.x) >> 6);
    int lane = threadIdx.x & 63;
    if (node >= n) return;
    int q = lane >> 3, r = lane & 7;
    int beg = offsets[node];
    int cnt = deg[node];
    float acc[8];
    #pragma unroll
    for (int k = 0; k < 8; k++) acc[k] = 0.f;
    for (int j = 0; j < cnt; j += 16) {
        int j0 = j + q, j1 = j + 8 + q;
        if (j0 < cnt) {
            int s = se[beg + j0].x;
            uint4 v = ((const uint4*)(zb + (size_t)s * 64))[r];
            float lo, hi;
            bf2x2(v.x, lo, hi); acc[0] += lo; acc[1] += hi;
            bf2x2(v.y, lo, hi); acc[2] += lo; acc[3] += hi;
            bf2x2(v.z, lo, hi); acc[4] += lo; acc[5] += hi;
            bf2x2(v.w, lo, hi); acc[6] += lo; acc[7] += hi;
        }
        if (j1 < cnt) {
            int s = se[beg + j1].x;
            uint4 v = ((const uint4*)(zb + (size_t)s * 64))[r];
            float lo, hi;
            bf2x2(v.x, lo, hi); acc[0] += lo; acc[1] += hi;
            bf2x2(v.y, lo, hi); acc[2] += lo; acc[3] += hi;
            bf2x2(v.z, lo, hi); acc[4] += lo; acc[5] += hi;
            bf2x2(v.w, lo, hi); acc[6] += lo; acc[7] += hi;
        }
    }
    #pragma unroll
    for (int off = 32; off >= 8; off >>= 1) {
        #pragma unroll
        for (int k = 0; k < 8; k++) acc[k] += __shfl_down(acc[k], off);
    }
    if (q == 0) {
        float dinv = 1.0f / fmaxf((float)cnt, 1.0f);
        uint4 hp = ((const uint4*)(h2part + (size_t)node * 64))[r];
        float h0, h1v, h2v, h3, h4, h5, h6, h7;
        bf2x2(hp.x, h0, h1v); bf2x2(hp.y, h2v, h3);
        bf2x2(hp.z, h4, h5);  bf2x2(hp.w, h6, h7);
        float4 ba = ((const float4*)b2)[2 * r];
        float4 bb = ((const float4*)b2)[2 * r + 1];
        uint4 o;
        o.x = pack2(h0 + dinv * acc[0] + ba.x, h1v + dinv * acc[1] + ba.y);
        o.y = pack2(h2v + dinv * acc[2] + ba.z, h3 + dinv * acc[3] + ba.w);
        o.z = pack2(h4 + dinv * acc[4] + bb.x, h5 + dinv * acc[5] + bb.y);
        o.w = pack2(h6 + dinv * acc[6] + bb.z, h7 + dinv * acc[7] + bb.w);
        ((uint4*)(h2 + (size_t)node * 64))[r] = o;
    }
}

// out[eid] = dot(h2[src], h2[dst]); 8 lanes/row, 16 edges per iteration
__global__ void edge_out(const int* __restrict__ offsets, const int* __restrict__ deg,
                         const int2* __restrict__ se,
                         const unsigned short* __restrict__ h2,
                         float* __restrict__ out, int n) {
    int node = (int)((blockIdx.x * (unsigned)blockDim.x + threadIdx.x) >> 6);
    int lane = threadIdx.x & 63;
    if (node >= n) return;
    int q = lane >> 3, r = lane & 7;
    int beg = offsets[node];
    int cnt = deg[node];
    uint4 du = ((const uint4*)(h2 + (size_t)node * 64))[r];
    float d0, d1, d2, d3, d4, d5, d6, d7;
    bf2x2(du.x, d0, d1); bf2x2(du.y, d2, d3);
    bf2x2(du.z, d4, d5); bf2x2(du.w, d6, d7);
    for (int j = 0; j < cnt; j += 16) {
        int j0 = j + q, j1 = j + 8 + q;
        bool v0 = j0 < cnt, v1 = j1 < cnt;
        int2 p0 = se[beg + (v0 ? j0 : 0)];
        int2 p1 = se[beg + (v1 ? j1 : 0)];
        float t0 = 0.f, t1 = 0.f;
        if (v0) {
            uint4 vu = ((const uint4*)(h2 + (size_t)p0.x * 64))[r];
            float lo, hi;
            bf2x2(vu.x, lo, hi); t0  = d0 * lo + d1 * hi;
            bf2x2(vu.y, lo, hi); t0 += d2 * lo + d3 * hi;
            bf2x2(vu.z, lo, hi); t0 += d4 * lo + d5 * hi;
            bf2x2(vu.w, lo, hi); t0 += d6 * lo + d7 * hi;
        }
        if (v1) {
            uint4 vu = ((const uint4*)(h2 + (size_t)p1.x * 64))[r];
            float lo, hi;
            bf2x2(vu.x, lo, hi); t1  = d0 * lo + d1 * hi;
            bf2x2(vu.y, lo, hi); t1 += d2 * lo + d3 * hi;
            bf2x2(vu.z, lo, hi); t1 += d4 * lo + d5 * hi;
            bf2x2(vu.w, lo, hi); t1 += d6 * lo + d7 * hi;
        }
        t0 += __shfl_down(t0, 4); t1 += __shfl_down(t1, 4);
        t0 += __shfl_down(t0, 2); t1 += __shfl_down(t1, 2);
        t0 += __shfl_down(t0, 1); t1 += __shfl_down(t1, 1);
        if (r == 0) {
            if (v0) out[p0.y] = t0;
            if (v1) out[p1.y] = t1;
        }
    }
}

extern "C" void kernel_launch(void* const* d_in, const int* in_sizes, int n_in,
                              void* d_out, int out_size, void* d_ws, size_t ws_size,
                              hipStream_t stream) {
    const float* x   = (const float*)d_in[0];
    const float* pos = (const float*)d_in[1];
    const int*   ei  = (const int*)d_in[2];
    const float* W1r = (const float*)d_in[3];
    const float* W1n = (const float*)d_in[4];
    const float* b1  = (const float*)d_in[5];
    const float* W2r = (const float*)d_in[6];
    const float* W2n = (const float*)d_in[7];
    const float* b2  = (const float*)d_in[8];
    float* out = (float*)d_out;
    const int E = in_sizes[2] / 2;
    const int N = N_NODES;

    // ---- workspace layout ----
    unsigned short* Abig  = (unsigned short*)d_ws;           // N*160 bf16 (16 MB)
    unsigned short* h1    = Abig + (size_t)N * KA;           // N*128 bf16
    unsigned short* zb    = h1 + (size_t)N * H1;             // N*64 bf16
    unsigned short* h2    = zb + (size_t)N * 64;             // N*64 bf16
    unsigned short* h2part = h2 + (size_t)N * 64;            // N*64 bf16
    unsigned short* Wt1   = h2part + (size_t)N * 64;         // 128*160
    unsigned short* Wt2   = Wt1 + 128 * KA;                  // 128*128
    int* bcount  = (int*)(Wt2 + 128 * 128);                  // 256
    int* bbase   = bcount + 256;                             // 256
    int* bcursor = bbase + 256;                              // 256
    int* offsets = bcursor + 256;                            // N
    int* deg     = offsets + N;                              // N
    int2* se     = (int2*)(deg + N + 2);                     // E pairs (8B-aligned)

    hipMemsetAsync(bcount, 0, 256 * sizeof(int), stream);

    wprep<<<dim3(16), dim3(256), 0, stream>>>(W1r, W1n, W2r, W2n, Wt1, Wt2);
    build_a<<<dim3((N * 64 + 255) / 256), dim3(256), 0, stream>>>(
        x, pos, (unsigned int*)Abig, N);

    bucket_hist<<<dim3(512), dim3(256), 0, stream>>>(ei, E, bcount);
    bucket_scan<<<dim3(1), dim3(256), 0, stream>>>(bcount, bbase, bcursor);
    coarse_scatter<<<dim3((E + CTILE - 1) / CTILE), dim3(256), 0, stream>>>(ei, E, bcursor, se);
    fine_sort<<<dim3(NBKT), dim3(256), 0, stream>>>(se, bbase, offsets, deg, N);

    gather_x<<<dim3((N + 3) / 4), dim3(256), 0, stream>>>(
        offsets, deg, se, pos, (unsigned int*)Abig, N);
    gemm1<<<dim3((N + 63) / 64), dim3(256), 0, stream>>>(Abig, Wt1, b1, h1, N);
    gemm2<<<dim3((N + 63) / 64), dim3(256), 0, stream>>>(h1, Wt2, h2part, zb, N);
    gather_z<<<dim3((N + 3) / 4), dim3(256), 0, stream>>>(
        offsets, deg, se, zb, h2part, b2, h2, N);
    edge_out<<<dim3((N + 3) / 4), dim3(256), 0, stream>>>(offsets, deg, se, h2, out, N);
}